// Round 2
// baseline (6142.981 us; speedup 1.0000x reference)
//
#include <hip/hip_runtime.h>

#define NN 1024
#define EE 4096
#define CAP 64
#define BD 64
#define NB (NN/BD)

__device__ __forceinline__ float waveReduceF(float v){
  for (int o = 32; o; o >>= 1) v += __shfl_down(v, o, 64);
  return v;
}
__device__ __forceinline__ double waveReduceD(double v){
  for (int o = 32; o; o >>= 1) v += __shfl_down(v, o, 64);
  return v;
}

// s_e = F_ee * s0_e ; sigma_e = F_ee^2 * Sigma0_ee + Cu_ee (diagonal structure, values read at runtime)
__global__ __launch_bounds__(256) void k_edge_init(const float* F, const float* Sg0, const float* Cu,
                                                   const float* s0, float* sv, float* sg){
  int e = blockIdx.x*256 + threadIdx.x;
  if (e < EE){
    float f = F[(size_t)e*EE + e];
    sv[e] = f * s0[e];
    sg[e] = f*f*Sg0[(size_t)e*EE + e] + Cu[(size_t)e*EE + e];
  }
}

// L = weighted Laplacian from edges; also adjacency lists
__global__ __launch_bounds__(256) void k_scatter(const int* edges, const float* sv,
                                                 float* L, int* cnt, int* nb, float* wg){
  int e = blockIdx.x*256 + threadIdx.x;
  if (e < EE){
    int n = edges[2*e], m = edges[2*e+1];
    float se = sv[e];
    atomicAdd(&L[(size_t)n*NN + n],  se);
    atomicAdd(&L[(size_t)m*NN + m],  se);
    atomicAdd(&L[(size_t)n*NN + m], -se);
    atomicAdd(&L[(size_t)m*NN + n], -se);
    int p1 = atomicAdd(&cnt[n], 1);
    if (p1 < CAP){ nb[n*CAP+p1] = m; wg[n*CAP+p1] = se; }
    int p2 = atomicAdd(&cnt[m], 1);
    if (p2 < CAP){ nb[m*CAP+p2] = n; wg[m*CAP+p2] = se; }
  }
}

// y = L x (sparse)
__global__ __launch_bounds__(256) void k_spmv(const float* L, const int* cnt, const int* nb, const float* wg,
                                              const float* x, float* y){
  int i = blockIdx.x*256 + threadIdx.x;
  if (i < NN){
    float acc = L[(size_t)i*NN + i] * x[i];
    int c = min(cnt[i], CAP);
    for (int t = 0; t < c; ++t) acc -= wg[i*CAP+t] * x[nb[i*CAP+t]];
    y[i] = acc;
  }
}

// Y[i,:] = (L X)[i,:] with L sparse, X dense  (L2 = L*L, L3 = L*L2)
__global__ __launch_bounds__(256) void k_srow(const float* L, const int* cnt, const int* nb, const float* wg,
                                              const float* X, float* Y){
  int i = blockIdx.x;
  __shared__ int   snb[CAP];
  __shared__ float swt[CAP];
  __shared__ float sdiag;
  int c = min(cnt[i], CAP);
  if ((int)threadIdx.x < c){ snb[threadIdx.x] = nb[i*CAP+threadIdx.x]; swt[threadIdx.x] = wg[i*CAP+threadIdx.x]; }
  if (threadIdx.x == 0) sdiag = L[(size_t)i*NN + i];
  __syncthreads();
  for (int j = threadIdx.x; j < NN; j += 256){
    float acc = sdiag * X[(size_t)i*NN + j];
    for (int t = 0; t < c; ++t) acc -= swt[t] * X[(size_t)snb[t]*NN + j];
    Y[(size_t)i*NN + j] = acc;
  }
}

// beta_{k,e} = sum_p dc_{p,e} * a[p+k+1]
__global__ __launch_bounds__(256) void k_beta(const int* edges, const float* cb, const float* a, float* bt){
  int e = blockIdx.x*256 + threadIdx.x;
  if (e < EE){
    int n = edges[2*e], m = edges[2*e+1];
    float dc0 = cb[n] - cb[m];
    float dc1 = cb[NN+n]   - cb[NN+m];
    float dc2 = cb[2*NN+n] - cb[2*NN+m];
    float dc3 = cb[3*NN+n] - cb[3*NN+m];
    float a1 = a[1], a2 = a[2], a3 = a[3], a4 = a[4];
    bt[e]        = dc0*a1 + dc1*a2 + dc2*a3 + dc3*a4;
    bt[EE+e]     = dc0*a2 + dc1*a3 + dc2*a4;
    bt[2*EE+e]   = dc0*a3 + dc1*a4;
    bt[3*EE+e]   = dc0*a4;
  }
}

// Ht[e,:] = H[:,e] = b0*u_e + b1*L u_e + b2*L2 u_e + b3*L3 u_e   (L^k symmetric -> row reads)
__global__ __launch_bounds__(256) void k_hbuild(const int* edges, const float* bt,
                                                const float* L, const float* L2, const float* L3, float* Ht){
  int e = blockIdx.x;
  int n = edges[2*e], m = edges[2*e+1];
  float b0 = bt[e], b1 = bt[EE+e], b2 = bt[2*EE+e], b3 = bt[3*EE+e];
  const float* Ln  = L  + (size_t)n*NN; const float* Lm  = L  + (size_t)m*NN;
  const float* L2n = L2 + (size_t)n*NN; const float* L2m = L2 + (size_t)m*NN;
  const float* L3n = L3 + (size_t)n*NN; const float* L3m = L3 + (size_t)m*NN;
  float* He = Ht + (size_t)e*NN;
  for (int j = threadIdx.x; j < NN; j += 256){
    float v = b1*(Ln[j]-Lm[j]) + b2*(L2n[j]-L2m[j]) + b3*(L3n[j]-L3m[j]);
    if (j == n) v += b0;
    if (j == m) v -= b0;
    He[j] = v;
  }
}

// Sd = (double)Cw
__global__ __launch_bounds__(256) void k_sinit(const float* Cw, double* Sd){
  size_t i = (size_t)blockIdx.x*256 + threadIdx.x;
  if (i < (size_t)NN*NN) Sd[i] = (double)Cw[i];
}

// Sd += Ht^T diag(sg) Ht in f64. Only lower + full 64-diag blocks (32x32 tiles).
__global__ __launch_bounds__(256) void k_sgemm(const float* Ht, const float* sg, double* Sd){
  if ((blockIdx.y >> 1) > (blockIdx.x >> 1)) return;   // keep lower + full 64-aligned diag blocks
  __shared__ double As[32][33];
  __shared__ double Bs[32][33];
  int i0 = blockIdx.x*32, j0 = blockIdx.y*32;
  int tid = threadIdx.x;
  int kk = tid >> 3, c4 = (tid & 7)*4;
  int tx = tid & 15, ty = tid >> 4;
  double a00=0, a01=0, a10=0, a11=0;
  for (int k0 = 0; k0 < EE; k0 += 32){
    const float* rowk = Ht + (size_t)(k0+kk)*NN;
    float4 va = *(const float4*)(rowk + i0 + c4);
    float4 vb = *(const float4*)(rowk + j0 + c4);
    double s = (double)sg[k0+kk];
    As[kk][c4+0] = va.x; As[kk][c4+1] = va.y; As[kk][c4+2] = va.z; As[kk][c4+3] = va.w;
    Bs[kk][c4+0] = vb.x*s; Bs[kk][c4+1] = vb.y*s; Bs[kk][c4+2] = vb.z*s; Bs[kk][c4+3] = vb.w*s;
    __syncthreads();
#pragma unroll
    for (int k = 0; k < 32; ++k){
      double x0 = As[k][tx*2], x1 = As[k][tx*2+1];
      double y0 = Bs[k][ty*2], y1 = Bs[k][ty*2+1];
      a00 += x0*y0; a01 += x0*y1; a10 += x1*y0; a11 += x1*y1;
    }
    __syncthreads();
  }
  size_t i = i0 + tx*2, j = j0 + ty*2;
  Sd[i*NN + j]     += a00; Sd[i*NN + j+1]     += a01;
  Sd[(i+1)*NN + j] += a10; Sd[(i+1)*NN + j+1] += a11;
}

// r = y - sum_p a_p c_p  (f64 out)
__global__ __launch_bounds__(256) void k_rvec(const float* y, const float* cb, const float* a, double* rz){
  int i = blockIdx.x*256 + threadIdx.x;
  if (i < NN){
    double acc = (double)y[i];
    for (int p = 0; p < 5; ++p) acc -= (double)a[p]*(double)cb[p*NN + i];
    rz[i] = acc;
  }
}

// LDL^T of 64x64 diag block, f64, one wave. Lower <- L (unit, stored w/o diag),
// diag <- d, upper stays = d*L^T (row j holds A^(j)[j,:]).
__global__ __launch_bounds__(64) void k_ldl_diag(double* Sd, int t){
  __shared__ double T[BD][BD+1];
  int off = t*BD, lane = threadIdx.x;
  for (int r = 0; r < BD; ++r) T[r][lane] = Sd[(size_t)(off+r)*NN + off + lane];
  __syncthreads();
  for (int j = 0; j < BD; ++j){
    double d = T[j][j];
    int i = lane;
    if (i > j){
      double l = T[j][i]/d;       // row j upper = A^(j)[j][i]; l_ij by symmetry
      T[i][j] = l;
      for (int k = j+1; k < BD; ++k) T[i][k] -= l*T[j][k];
    }
    __syncthreads();
  }
  for (int r = 0; r < BD; ++r) Sd[(size_t)(off+r)*NN + off + lane] = T[r][lane];
}

// Panel rows: L21 = A21 * L11^{-T} * D^{-1} (per-row substitution; v kept undivided)
__global__ __launch_bounds__(64) void k_ldl_panel(double* Sd, int t){
  __shared__ double T[BD][BD+1];
  __shared__ double XC[64][33];
  int off = t*BD, tid = threadIdx.x;
  for (int r = 0; r < BD; ++r) T[r][tid] = Sd[(size_t)(off+r)*NN + off + tid];
  __syncthreads();
  size_t i = (size_t)(off + BD + blockIdx.x*64 + tid);
  double* row = &Sd[i*NN + off];
  for (int ch = 0; ch < 2; ++ch){
    int base = ch*32;
    for (int jj = 0; jj < 32; ++jj){
      int j = base + jj;
      double acc = row[j];
      for (int k = 0; k < base; ++k) acc -= row[k]*T[k][k]*T[j][k];  // row[k]=L -> v_k = L*d_k
      for (int k = 0; k < jj; ++k)   acc -= XC[tid][k]*T[j][base+k]; // undivided v
      XC[tid][jj] = acc;
    }
    for (int k = 0; k < 32; ++k) row[base+k] = XC[tid][k]/T[base+k][base+k];
  }
}

// Trailing: A22 -= L21 * D * L21^T  (lower tiles only; scale B tile by d)
__global__ __launch_bounds__(256) void k_ldl_trail(double* Sd, int t){
  if (blockIdx.y > blockIdx.x) return;
  __shared__ double Ap[64][33];
  __shared__ double Bp[64][33];
  __shared__ double ds[BD];
  int off = t*BD, off2 = off + BD;
  int ib = off2 + blockIdx.x*64, jb = off2 + blockIdx.y*64;
  int tid = threadIdx.x;
  if (tid < BD) ds[tid] = Sd[(size_t)(off+tid)*NN + off + tid];
  __syncthreads();
  int tx = tid & 15, ty = tid >> 4;
  double acc[4][4] = {};
  for (int kc = 0; kc < BD; kc += 32){
#pragma unroll
    for (int l = 0; l < 2; ++l){
      int idx = tid + 256*l;            // 512 slots x 4 doubles = 2048
      int r = idx >> 3, k2 = (idx & 7)*4;
      const double* pa = &Sd[(size_t)(ib+r)*NN + off + kc + k2];
      const double* pb = &Sd[(size_t)(jb+r)*NN + off + kc + k2];
#pragma unroll
      for (int q = 0; q < 4; ++q){
        Ap[r][k2+q] = pa[q];
        Bp[r][k2+q] = pb[q]*ds[kc+k2+q];
      }
    }
    __syncthreads();
#pragma unroll
    for (int k = 0; k < 32; ++k){
      double av[4], bv[4];
#pragma unroll
      for (int q = 0; q < 4; ++q){ av[q] = Ap[tx*4+q][k]; bv[q] = Bp[ty*4+q][k]; }
#pragma unroll
      for (int r2 = 0; r2 < 4; ++r2)
#pragma unroll
        for (int c2 = 0; c2 < 4; ++c2)
          acc[r2][c2] += av[r2]*bv[c2];
    }
    __syncthreads();
  }
#pragma unroll
  for (int r2 = 0; r2 < 4; ++r2)
#pragma unroll
    for (int c2 = 0; c2 < 4; ++c2)
      Sd[(size_t)(ib+tx*4+r2)*NN + jb + ty*4 + c2] -= acc[r2][c2];
}

// Forward block step: z_blk = L11^{-1} r_blk (unit L; wave-shuffle substitution), r_rest -= L21 z_blk
__global__ __launch_bounds__(256) void k_fwd(const double* Sd, double* rz, int t){
  __shared__ double T[BD][BD+1];
  __shared__ double wls[BD];
  int off = t*BD, tid = threadIdx.x, lane = tid & 63, wv = tid >> 6;
  for (int idx = tid; idx < BD*BD; idx += 256){
    int r = idx >> 6, c = idx & 63;
    T[r][c] = Sd[(size_t)(off+r)*NN + off + c];
  }
  __syncthreads();
  if (wv == 0){
    double r = rz[off + lane];
    for (int j = 0; j < BD; ++j){
      double wj = __shfl(r, j, 64) / T[j][j];   // z_j / d_j
      if (lane > j) r -= T[j][lane]*wj;          // upper row j = d_j * l_{lane,j}
    }
    wls[lane] = r;
    rz[off + lane] = r;
  }
  __syncthreads();
  for (int i = off + BD + wv; i < NN; i += 4){
    double acc = Sd[(size_t)i*NN + off + lane]*wls[lane];
    acc = waveReduceD(acc);
    if (lane == 0) rz[i] -= acc;
  }
}

// w = z / d
__global__ __launch_bounds__(256) void k_ddiv(const double* Sd, double* rz){
  int i = blockIdx.x*256 + threadIdx.x;
  if (i < NN) rz[i] /= Sd[(size_t)i*NN + i];
}

// Backward block step on L^T (unit), then update earlier blocks
__global__ __launch_bounds__(256) void k_bwd(const double* Sd, double* rz, int t){
  __shared__ double T[BD][BD+1];
  __shared__ double wls[BD];
  int off = t*BD, tid = threadIdx.x, lane = tid & 63, wv = tid >> 6;
  for (int idx = tid; idx < BD*BD; idx += 256){
    int r = idx >> 6, c = idx & 63;
    T[r][c] = Sd[(size_t)(off+r)*NN + off + c];
  }
  __syncthreads();
  if (wv == 0){
    double x = rz[off + lane];
    for (int j = BD-1; j >= 0; --j){
      double xj = __shfl(x, j, 64);
      if (lane < j) x -= T[j][lane]*xj;          // lower row j = l_{j,lane}
    }
    wls[lane] = x;
    rz[off + lane] = x;
  }
  __syncthreads();
  for (int i = tid; i < off; i += 256){
    double acc = 0.0;
    for (int j = 0; j < BD; ++j) acc += Sd[(size_t)(off+j)*NN + i]*wls[j];
    rz[i] -= acc;
  }
}

// s_out = relu(s + sigma .* (Ht z))
__global__ __launch_bounds__(256) void k_snew(const float* Ht, const float* sv, const float* sg,
                                              const double* z, float* out){
  int e = blockIdx.x*4 + (threadIdx.x >> 6);
  int lane = threadIdx.x & 63;
  const float* He = Ht + (size_t)e*NN;
  double acc = 0.0;
  for (int j = lane; j < NN; j += 64) acc += (double)He[j]*z[j];
  acc = waveReduceD(acc);
  if (lane == 0){
    double val = (double)sv[e] + (double)sg[e]*acc;
    out[e] = fmaxf((float)val, 0.0f);
  }
}

extern "C" void kernel_launch(void* const* d_in, const int* in_sizes, int n_in,
                              void* d_out, int out_size, void* d_ws, size_t ws_size,
                              hipStream_t stream){
  const float* q   = (const float*)d_in[0];
  const float* y   = (const float*)d_in[1];
  const float* F   = (const float*)d_in[2];
  // d_in[3] = B (incidence) — structure carried by edges
  const int*   edges = (const int*)d_in[4];
  const float* Cu  = (const float*)d_in[5];
  const float* Cw  = (const float*)d_in[6];
  const float* s0  = (const float*)d_in[7];
  const float* Sg0 = (const float*)d_in[8];
  const float* a   = (const float*)d_in[9];
  float* out = (float*)d_out;

  double* Sd = (double*)d_ws;                 // 1M f64 (8 MB), 8B-aligned at base
  double* rz = Sd + (size_t)NN*NN;            // NN f64
  float* w = (float*)(rz + NN);
  float* L  = w; w += (size_t)NN*NN;
  float* L2 = w; w += (size_t)NN*NN;
  float* L3 = w; w += (size_t)NN*NN;
  float* Ht = w; w += (size_t)EE*NN;
  float* cb = w; w += 5*NN;
  float* sv = w; w += EE;
  float* sg = w; w += EE;
  float* bt = w; w += 4*EE;
  float* wg = w; w += (size_t)NN*CAP;
  int* cnt  = (int*)w; w += NN;
  int* nb   = (int*)w; w += (size_t)NN*CAP;

  hipMemsetAsync(L, 0, (size_t)NN*NN*sizeof(float), stream);
  hipMemsetAsync(cnt, 0, NN*sizeof(int), stream);

  k_edge_init<<<EE/256, 256, 0, stream>>>(F, Sg0, Cu, s0, sv, sg);
  k_scatter<<<EE/256, 256, 0, stream>>>(edges, sv, L, cnt, nb, wg);

  hipMemcpyAsync(cb, q, NN*sizeof(float), hipMemcpyDeviceToDevice, stream);
  for (int p = 1; p < 5; ++p)
    k_spmv<<<NN/256, 256, 0, stream>>>(L, cnt, nb, wg, cb + (p-1)*NN, cb + p*NN);

  k_srow<<<NN, 256, 0, stream>>>(L, cnt, nb, wg, L,  L2);
  k_srow<<<NN, 256, 0, stream>>>(L, cnt, nb, wg, L2, L3);

  k_beta<<<EE/256, 256, 0, stream>>>(edges, cb, a, bt);
  k_hbuild<<<EE, 256, 0, stream>>>(edges, bt, L, L2, L3, Ht);

  k_sinit<<<(NN*NN)/256, 256, 0, stream>>>(Cw, Sd);
  dim3 gg(NN/32, NN/32);
  k_sgemm<<<gg, 256, 0, stream>>>(Ht, sg, Sd);

  k_rvec<<<NN/256, 256, 0, stream>>>(y, cb, a, rz);

  for (int t = 0; t < NB; ++t){
    k_ldl_diag<<<1, 64, 0, stream>>>(Sd, t);
    int nt = NB - 1 - t;
    if (nt > 0){
      k_ldl_panel<<<nt, 64, 0, stream>>>(Sd, t);
      dim3 tg(nt, nt);
      k_ldl_trail<<<tg, 256, 0, stream>>>(Sd, t);
    }
  }
  for (int t = 0; t < NB; ++t)      k_fwd<<<1, 256, 0, stream>>>(Sd, rz, t);
  k_ddiv<<<NN/256, 256, 0, stream>>>(Sd, rz);
  for (int t = NB-1; t >= 0; --t)   k_bwd<<<1, 256, 0, stream>>>(Sd, rz, t);

  k_snew<<<EE/4, 256, 0, stream>>>(Ht, sv, sg, rz, out);
}

// Round 3
// 4066.482 us; speedup vs baseline: 1.5106x; 1.5106x over previous
//
#include <hip/hip_runtime.h>

#define NN 1024
#define EE 4096
#define CAP 64
#define BD 64
#define NB (NN/BD)
#define KSPLIT 4
#define NTILE 136
#define GRIDN 128

__device__ __forceinline__ double waveReduceD(double v){
  for (int o = 32; o; o >>= 1) v += __shfl_down(v, o, 64);
  return v;
}

// s_e = F_ee * s0_e ; sigma_e = F_ee^2 * Sigma0_ee + Cu_ee (diagonal structure, values read at runtime)
__global__ __launch_bounds__(256) void k_edge_init(const float* F, const float* Sg0, const float* Cu,
                                                   const float* s0, float* sv, float* sg){
  int e = blockIdx.x*256 + threadIdx.x;
  if (e < EE){
    float f = F[(size_t)e*EE + e];
    sv[e] = f * s0[e];
    sg[e] = f*f*Sg0[(size_t)e*EE + e] + Cu[(size_t)e*EE + e];
  }
}

// L = weighted Laplacian from edges; also adjacency lists
__global__ __launch_bounds__(256) void k_scatter(const int* edges, const float* sv,
                                                 float* L, int* cnt, int* nb, float* wg){
  int e = blockIdx.x*256 + threadIdx.x;
  if (e < EE){
    int n = edges[2*e], m = edges[2*e+1];
    float se = sv[e];
    atomicAdd(&L[(size_t)n*NN + n],  se);
    atomicAdd(&L[(size_t)m*NN + m],  se);
    atomicAdd(&L[(size_t)n*NN + m], -se);
    atomicAdd(&L[(size_t)m*NN + n], -se);
    int p1 = atomicAdd(&cnt[n], 1);
    if (p1 < CAP){ nb[n*CAP+p1] = m; wg[n*CAP+p1] = se; }
    int p2 = atomicAdd(&cnt[m], 1);
    if (p2 < CAP){ nb[m*CAP+p2] = n; wg[m*CAP+p2] = se; }
  }
}

// y = L x (sparse)
__global__ __launch_bounds__(256) void k_spmv(const float* L, const int* cnt, const int* nb, const float* wg,
                                              const float* x, float* y){
  int i = blockIdx.x*256 + threadIdx.x;
  if (i < NN){
    float acc = L[(size_t)i*NN + i] * x[i];
    int c = min(cnt[i], CAP);
    for (int t = 0; t < c; ++t) acc -= wg[i*CAP+t] * x[nb[i*CAP+t]];
    y[i] = acc;
  }
}

// Y[i,:] = (L X)[i,:] with L sparse, X dense  (L2 = L*L, L3 = L*L2)
__global__ __launch_bounds__(256) void k_srow(const float* L, const int* cnt, const int* nb, const float* wg,
                                              const float* X, float* Y){
  int i = blockIdx.x;
  __shared__ int   snb[CAP];
  __shared__ float swt[CAP];
  __shared__ float sdiag;
  int c = min(cnt[i], CAP);
  if ((int)threadIdx.x < c){ snb[threadIdx.x] = nb[i*CAP+threadIdx.x]; swt[threadIdx.x] = wg[i*CAP+threadIdx.x]; }
  if (threadIdx.x == 0) sdiag = L[(size_t)i*NN + i];
  __syncthreads();
  for (int j = threadIdx.x; j < NN; j += 256){
    float acc = sdiag * X[(size_t)i*NN + j];
    for (int t = 0; t < c; ++t) acc -= swt[t] * X[(size_t)snb[t]*NN + j];
    Y[(size_t)i*NN + j] = acc;
  }
}

// beta_{k,e} = sum_p dc_{p,e} * a[p+k+1]
__global__ __launch_bounds__(256) void k_beta(const int* edges, const float* cb, const float* a, float* bt){
  int e = blockIdx.x*256 + threadIdx.x;
  if (e < EE){
    int n = edges[2*e], m = edges[2*e+1];
    float dc0 = cb[n] - cb[m];
    float dc1 = cb[NN+n]   - cb[NN+m];
    float dc2 = cb[2*NN+n] - cb[2*NN+m];
    float dc3 = cb[3*NN+n] - cb[3*NN+m];
    float a1 = a[1], a2 = a[2], a3 = a[3], a4 = a[4];
    bt[e]        = dc0*a1 + dc1*a2 + dc2*a3 + dc3*a4;
    bt[EE+e]     = dc0*a2 + dc1*a3 + dc2*a4;
    bt[2*EE+e]   = dc0*a3 + dc1*a4;
    bt[3*EE+e]   = dc0*a4;
  }
}

// Ht[e,:] = H[:,e] = b0*u_e + b1*L u_e + b2*L2 u_e + b3*L3 u_e   (L^k symmetric -> row reads)
__global__ __launch_bounds__(256) void k_hbuild(const int* edges, const float* bt,
                                                const float* L, const float* L2, const float* L3, float* Ht){
  int e = blockIdx.x;
  int n = edges[2*e], m = edges[2*e+1];
  float b0 = bt[e], b1 = bt[EE+e], b2 = bt[2*EE+e], b3 = bt[3*EE+e];
  const float* Ln  = L  + (size_t)n*NN; const float* Lm  = L  + (size_t)m*NN;
  const float* L2n = L2 + (size_t)n*NN; const float* L2m = L2 + (size_t)m*NN;
  const float* L3n = L3 + (size_t)n*NN; const float* L3m = L3 + (size_t)m*NN;
  float* He = Ht + (size_t)e*NN;
  for (int j = threadIdx.x; j < NN; j += 256){
    float v = b1*(Ln[j]-Lm[j]) + b2*(L2n[j]-L2m[j]) + b3*(L3n[j]-L3m[j]);
    if (j == n) v += b0;
    if (j == m) v -= b0;
    He[j] = v;
  }
}

__device__ __forceinline__ void tri_decode(int p, int& ti, int& tj){
  ti = (int)((sqrtf(8.f*p + 1.f) - 1.f)*0.5f);
  while ((ti+1)*(ti+2)/2 <= p) ti++;
  while (ti*(ti+1)/2 > p) ti--;
  tj = p - ti*(ti+1)/2;
}

// Spart[z][p] = (Ht^T diag(sg) Ht) 64x64 tile (ti,tj), K-chunk z. f32 loads, f64 LDS + acc.
__global__ __launch_bounds__(256,2) void k_sgemm2(const float* Ht, const float* sg, double* Spart){
  int p = blockIdx.x, z = blockIdx.y;
  int ti, tj; tri_decode(p, ti, tj);
  int i0 = ti*64, j0 = tj*64;
  __shared__ double As[32][66];
  __shared__ double Bs[32][66];
  int tid = threadIdx.x;
  int tx = tid & 15, ty = tid >> 4;
  double acc[4][4] = {};
  int kbase = z*(EE/KSPLIT);
  for (int k0 = kbase; k0 < kbase + EE/KSPLIT; k0 += 32){
#pragma unroll
    for (int l = 0; l < 2; ++l){
      int s = tid + 256*l;
      int kk = s >> 4, g = s & 15;
      const float* row = Ht + (size_t)(k0+kk)*NN;
      float4 va = *(const float4*)(row + i0 + g*4);
      float4 vb = *(const float4*)(row + j0 + g*4);
      double sgd = (double)sg[k0+kk];
      As[kk][g*4+0] = (double)va.x; As[kk][g*4+1] = (double)va.y;
      As[kk][g*4+2] = (double)va.z; As[kk][g*4+3] = (double)va.w;
      Bs[kk][g*4+0] = (double)vb.x*sgd; Bs[kk][g*4+1] = (double)vb.y*sgd;
      Bs[kk][g*4+2] = (double)vb.z*sgd; Bs[kk][g*4+3] = (double)vb.w*sgd;
    }
    __syncthreads();
#pragma unroll
    for (int kk = 0; kk < 32; ++kk){
      double av[4], bv[4];
#pragma unroll
      for (int q = 0; q < 4; ++q){ av[q] = As[kk][tx*4+q]; bv[q] = Bs[kk][ty*4+q]; }
#pragma unroll
      for (int r = 0; r < 4; ++r)
#pragma unroll
        for (int c = 0; c < 4; ++c)
          acc[r][c] += av[r]*bv[c];
    }
    __syncthreads();
  }
  double* out = Spart + ((size_t)z*NTILE + p)*4096;
#pragma unroll
  for (int r = 0; r < 4; ++r)
#pragma unroll
    for (int c = 0; c < 4; ++c)
      out[(tx*4+r)*64 + ty*4+c] = acc[r][c];
}

// Sd tile(ti,tj) = sum_z Spart + Cw  (lower tiles; diag tiles full square)
__global__ __launch_bounds__(256) void k_sreduce(const double* Spart, const float* Cw, double* Sd){
  int p = blockIdx.x;
  int ti, tj; tri_decode(p, ti, tj);
  int tid = threadIdx.x;
  for (int idx = tid; idx < 4096; idx += 256){
    int r = idx >> 6, c = idx & 63;
    size_t gi = ti*64 + r, gj = tj*64 + c;
    double v = (double)Cw[gi*NN + gj];
#pragma unroll
    for (int z = 0; z < KSPLIT; ++z)
      v += Spart[((size_t)z*NTILE + p)*4096 + idx];
    Sd[gi*NN + gj] = v;
  }
}

// r = y - sum_p a_p c_p  (f64 out)
__global__ __launch_bounds__(256) void k_rvec(const float* y, const float* cb, const float* a, double* rz){
  int i = blockIdx.x*256 + threadIdx.x;
  if (i < NN){
    double acc = (double)y[i];
    for (int p = 0; p < 5; ++p) acc -= (double)a[p]*(double)cb[p*NN + i];
    rz[i] = acc;
  }
}

// ---------------- persistent LDL^T + solve kernel ----------------
// Sd lower+diag maintained. Factored diag tiles: lower=L, diag=d, upper=L^T.
// grd[i] = 1/d_i. Grid barrier: device-scope epoch counter.
__global__ __launch_bounds__(256,2) void k_solver(double* Sd, double* rz, double* grd, int* bar){
  __shared__ double T[BD][BD+1];
  __shared__ double R[BD][BD+1];
  __shared__ double dsh[BD];
  int bid = blockIdx.x, tid = threadIdx.x;
  int ep = 0;

#define GBAR() do{ \
    __syncthreads(); \
    ep++; \
    if (tid == 0){ \
      __hip_atomic_fetch_add(bar, 1, __ATOMIC_ACQ_REL, __HIP_MEMORY_SCOPE_AGENT); \
      while (__hip_atomic_load(bar, __ATOMIC_ACQUIRE, __HIP_MEMORY_SCOPE_AGENT) < ep*GRIDN) \
        __builtin_amdgcn_s_sleep(2); \
    } \
    __syncthreads(); \
  }while(0)

  // factor T (in LDS) for tile at row/col offset off0; write L/d/L^T back + grd
#define FACTOR_WB(off0) do{ \
    __syncthreads(); \
    for (int j = 0; j < BD; ++j){ \
      double dj = T[j][j]; \
      int fi = tid & 63, cg = tid >> 6; \
      double l = T[j][fi] / dj; \
      if (fi > j){ \
        for (int c = j+1+cg; c < BD; c += 4) T[fi][c] -= l*T[j][c]; \
      } \
      __syncthreads(); \
    } \
    if (tid < BD) dsh[tid] = 1.0 / T[tid][tid]; \
    __syncthreads(); \
    for (int idx = tid; idx < BD*BD; idx += 256){ \
      int r = idx >> 6, c = idx & 63; \
      double v = (r == c) ? T[r][r] : (r > c ? T[r][c]*dsh[c] : T[r][c]*dsh[r]); \
      Sd[(size_t)((off0)+r)*NN + (off0) + c] = v; \
    } \
    if (tid < BD) grd[(off0)+tid] = dsh[tid]; \
  }while(0)

  // ---- factor tile 0
  if (bid == 0){
    for (int idx = tid; idx < BD*BD; idx += 256){
      int r = idx >> 6, c = idx & 63;
      T[r][c] = Sd[(size_t)r*NN + c];
    }
    FACTOR_WB(0);
  }
  GBAR();

  for (int t = 0; t < NB-1; ++t){
    int off = t*BD, off2 = off + BD;
    int nt = NB-1-t;
    // ---- panel: row-chunk bid of 64 rows solves vs factored tile t
    if (bid < nt){
      for (int idx = tid; idx < BD*BD; idx += 256){
        int r = idx >> 6, c = idx & 63;
        T[r][c] = Sd[(size_t)(off+r)*NN + off + c];
      }
      if (tid < BD) dsh[tid] = grd[off+tid];
      __syncthreads();
      int r0 = off2 + bid*BD;
      for (int idx = tid; idx < BD*BD; idx += 256){
        int r = idx >> 6, c = idx & 63;
        R[r][c] = Sd[(size_t)(r0+r)*NN + off + c];
      }
      __syncthreads();
      if (tid < BD){
        for (int j = 0; j < BD; ++j){
          double acc = R[tid][j];
          for (int k = 0; k < j; ++k) acc -= R[tid][k]*T[j][k];
          R[tid][j] = acc;                      // u_j (undivided)
        }
      }
      __syncthreads();
      for (int idx = tid; idx < BD*BD; idx += 256){
        int r = idx >> 6, c = idx & 63;
        Sd[(size_t)(r0+r)*NN + off + c] = R[r][c]*dsh[c];
      }
    }
    GBAR();
    // ---- trailing update; block 0 also factors next diag tile
    int tx = tid & 15, ty = tid >> 4;
    if (bid == 0){
      // job (t+1,t+1): T_new = A - P D P^T, factor in LDS
      if (tid < BD) dsh[tid] = Sd[(size_t)(off+tid)*NN + off + tid];
      __syncthreads();
      for (int idx = tid; idx < BD*BD; idx += 256){
        int r = idx >> 6, c = idx & 63;
        R[r][c] = Sd[(size_t)(off2+r)*NN + off + c];   // P rows
      }
      __syncthreads();
      double acc[4][4] = {};
      for (int k = 0; k < BD; ++k){
        double dk = dsh[k];
        double av[4], bv[4];
#pragma unroll
        for (int q = 0; q < 4; ++q){ av[q] = R[tx*4+q][k]; bv[q] = R[ty*4+q][k]*dk; }
#pragma unroll
        for (int r = 0; r < 4; ++r)
#pragma unroll
          for (int c = 0; c < 4; ++c)
            acc[r][c] += av[r]*bv[c];
      }
      __syncthreads();
#pragma unroll
      for (int r = 0; r < 4; ++r)
#pragma unroll
        for (int c = 0; c < 4; ++c)
          T[tx*4+r][ty*4+c] = Sd[(size_t)(off2+tx*4+r)*NN + off2 + ty*4+c] - acc[r][c];
      FACTOR_WB(off2);
    } else {
      int m = NB-1-t;                    // panel tiles below diag t
      int total = m*(m+1)/2;             // jobs (ii>=jj) in trailing block-triangle
      for (int q = bid; q < total; q += GRIDN-1){   // q>=1 always: (0,0)=(t+1,t+1) is block 0's
        int ii, jj; tri_decode(q, ii, jj);
        int I = off2 + ii*BD, J = off2 + jj*BD;
        __syncthreads();
        if (tid < BD) dsh[tid] = Sd[(size_t)(off+tid)*NN + off + tid];
        __syncthreads();
        for (int idx = tid; idx < BD*BD; idx += 256){
          int r = idx >> 6, c = idx & 63;
          T[r][c] = Sd[(size_t)(I+r)*NN + off + c];                 // P_I
          R[r][c] = Sd[(size_t)(J+r)*NN + off + c] * dsh[c];        // P_J * d
        }
        __syncthreads();
        double acc[4][4] = {};
        for (int k = 0; k < BD; ++k){
          double av[4], bv[4];
#pragma unroll
          for (int q2 = 0; q2 < 4; ++q2){ av[q2] = T[tx*4+q2][k]; bv[q2] = R[ty*4+q2][k]; }
#pragma unroll
          for (int r = 0; r < 4; ++r)
#pragma unroll
            for (int c = 0; c < 4; ++c)
              acc[r][c] += av[r]*bv[c];
        }
#pragma unroll
        for (int r = 0; r < 4; ++r)
#pragma unroll
          for (int c = 0; c < 4; ++c){
            size_t o = (size_t)(I+tx*4+r)*NN + J + ty*4+c;
            Sd[o] -= acc[r][c];
          }
      }
    }
    GBAR();
  }

  // ---- triangular solves, block 0 only
  if (bid == 0){
    int lane = tid & 63, wv = tid >> 6;
    // forward: L u = r (unit lower)
    for (int t = 0; t < NB; ++t){
      int off = t*BD;
      for (int idx = tid; idx < BD*BD; idx += 256){
        int r = idx >> 6, c = idx & 63;
        T[r][c] = Sd[(size_t)(off+r)*NN + off + c];
      }
      __syncthreads();
      if (wv == 0){
        double x = rz[off + lane];
        for (int j = 0; j < BD; ++j){
          double xj = __shfl(x, j, 64);
          if (lane > j) x -= T[j][lane]*xj;     // upper = L^T
        }
        dsh[lane] = x; rz[off + lane] = x;
      }
      __syncthreads();
      for (int i = off + BD + wv; i < NN; i += 4){
        double acc = Sd[(size_t)i*NN + off + lane]*dsh[lane];
        acc = waveReduceD(acc);
        if (lane == 0) rz[i] -= acc;
      }
      __syncthreads();
    }
    // diag
    for (int i = tid; i < NN; i += 256) rz[i] *= grd[i];
    __syncthreads();
    // backward: L^T z = w
    for (int t = NB-1; t >= 0; --t){
      int off = t*BD;
      for (int idx = tid; idx < BD*BD; idx += 256){
        int r = idx >> 6, c = idx & 63;
        T[r][c] = Sd[(size_t)(off+r)*NN + off + c];
      }
      __syncthreads();
      if (wv == 0){
        double x = rz[off + lane];
        for (int j = BD-1; j >= 0; --j){
          double xj = __shfl(x, j, 64);
          if (lane < j) x -= T[j][lane]*xj;     // lower = L
        }
        dsh[lane] = x; rz[off + lane] = x;
      }
      __syncthreads();
      for (int i = tid; i < off; i += 256){
        double acc = 0.0;
        for (int j = 0; j < BD; ++j) acc += Sd[(size_t)(off+j)*NN + i]*dsh[j];
        rz[i] -= acc;
      }
      __syncthreads();
    }
  }
#undef GBAR
#undef FACTOR_WB
}

// s_out = relu(s + sigma .* (Ht z))
__global__ __launch_bounds__(256) void k_snew(const float* Ht, const float* sv, const float* sg,
                                              const double* z, float* out){
  int e = blockIdx.x*4 + (threadIdx.x >> 6);
  int lane = threadIdx.x & 63;
  const float* He = Ht + (size_t)e*NN;
  double acc = 0.0;
  for (int j = lane; j < NN; j += 64) acc += (double)He[j]*z[j];
  acc = waveReduceD(acc);
  if (lane == 0){
    double val = (double)sv[e] + (double)sg[e]*acc;
    out[e] = fmaxf((float)val, 0.0f);
  }
}

extern "C" void kernel_launch(void* const* d_in, const int* in_sizes, int n_in,
                              void* d_out, int out_size, void* d_ws, size_t ws_size,
                              hipStream_t stream){
  const float* q   = (const float*)d_in[0];
  const float* y   = (const float*)d_in[1];
  const float* F   = (const float*)d_in[2];
  // d_in[3] = B (incidence) — structure carried by edges
  const int*   edges = (const int*)d_in[4];
  const float* Cu  = (const float*)d_in[5];
  const float* Cw  = (const float*)d_in[6];
  const float* s0  = (const float*)d_in[7];
  const float* Sg0 = (const float*)d_in[8];
  const float* a   = (const float*)d_in[9];
  float* out = (float*)d_out;

  double* Sd    = (double*)d_ws;                       // 8 MB
  double* Spart = Sd + (size_t)NN*NN;                  // 17.8 MB
  double* rz    = Spart + (size_t)KSPLIT*NTILE*4096;
  double* grd   = rz + NN;
  float* w = (float*)(grd + NN);
  float* L  = w; w += (size_t)NN*NN;
  float* L2 = w; w += (size_t)NN*NN;
  float* L3 = w; w += (size_t)NN*NN;
  float* Ht = w; w += (size_t)EE*NN;
  float* cb = w; w += 5*NN;
  float* sv = w; w += EE;
  float* sg = w; w += EE;
  float* bt = w; w += 4*EE;
  float* wg = w; w += (size_t)NN*CAP;
  int* cnt  = (int*)w; w += NN;
  int* nb   = (int*)w; w += (size_t)NN*CAP;
  int* bar  = (int*)w; w += 64;

  hipMemsetAsync(L, 0, (size_t)NN*NN*sizeof(float), stream);
  hipMemsetAsync(cnt, 0, NN*sizeof(int), stream);
  hipMemsetAsync(bar, 0, 64*sizeof(int), stream);

  k_edge_init<<<EE/256, 256, 0, stream>>>(F, Sg0, Cu, s0, sv, sg);
  k_scatter<<<EE/256, 256, 0, stream>>>(edges, sv, L, cnt, nb, wg);

  hipMemcpyAsync(cb, q, NN*sizeof(float), hipMemcpyDeviceToDevice, stream);
  for (int p = 1; p < 5; ++p)
    k_spmv<<<NN/256, 256, 0, stream>>>(L, cnt, nb, wg, cb + (p-1)*NN, cb + p*NN);

  k_srow<<<NN, 256, 0, stream>>>(L, cnt, nb, wg, L,  L2);
  k_srow<<<NN, 256, 0, stream>>>(L, cnt, nb, wg, L2, L3);

  k_beta<<<EE/256, 256, 0, stream>>>(edges, cb, a, bt);
  k_hbuild<<<EE, 256, 0, stream>>>(edges, bt, L, L2, L3, Ht);

  dim3 gg(NTILE, KSPLIT);
  k_sgemm2<<<gg, 256, 0, stream>>>(Ht, sg, Spart);
  k_sreduce<<<NTILE, 256, 0, stream>>>(Spart, Cw, Sd);

  k_rvec<<<NN/256, 256, 0, stream>>>(y, cb, a, rz);

  k_solver<<<GRIDN, 256, 0, stream>>>(Sd, rz, grd, bar);

  k_snew<<<EE/4, 256, 0, stream>>>(Ht, sv, sg, rz, out);
}

// Round 4
// 2810.877 us; speedup vs baseline: 2.1854x; 1.4467x over previous
//
#include <hip/hip_runtime.h>

#define NN 1024
#define EE 4096
#define CAP 64
#define BD 64
#define NB (NN/BD)
#define KSPLIT 4
#define NTILE 136
#define GRIDN 128

__device__ __forceinline__ double waveReduceD(double v){
  for (int o = 32; o; o >>= 1) v += __shfl_down(v, o, 64);
  return v;
}

// s_e = F_ee * s0_e ; sigma_e = F_ee^2 * Sigma0_ee + Cu_ee (diagonal structure, values read at runtime)
__global__ __launch_bounds__(256) void k_edge_init(const float* __restrict__ F, const float* __restrict__ Sg0,
                                                   const float* __restrict__ Cu, const float* __restrict__ s0,
                                                   float* __restrict__ sv, float* __restrict__ sg){
  int e = blockIdx.x*256 + threadIdx.x;
  if (e < EE){
    float f = F[(size_t)e*EE + e];
    sv[e] = f * s0[e];
    sg[e] = f*f*Sg0[(size_t)e*EE + e] + Cu[(size_t)e*EE + e];
  }
}

// L = weighted Laplacian from edges; also adjacency lists
__global__ __launch_bounds__(256) void k_scatter(const int* __restrict__ edges, const float* __restrict__ sv,
                                                 float* __restrict__ L, int* __restrict__ cnt,
                                                 int* __restrict__ nb, float* __restrict__ wg){
  int e = blockIdx.x*256 + threadIdx.x;
  if (e < EE){
    int n = edges[2*e], m = edges[2*e+1];
    float se = sv[e];
    atomicAdd(&L[(size_t)n*NN + n],  se);
    atomicAdd(&L[(size_t)m*NN + m],  se);
    atomicAdd(&L[(size_t)n*NN + m], -se);
    atomicAdd(&L[(size_t)m*NN + n], -se);
    int p1 = atomicAdd(&cnt[n], 1);
    if (p1 < CAP){ nb[n*CAP+p1] = m; wg[n*CAP+p1] = se; }
    int p2 = atomicAdd(&cnt[m], 1);
    if (p2 < CAP){ nb[m*CAP+p2] = n; wg[m*CAP+p2] = se; }
  }
}

// y = L x (sparse)
__global__ __launch_bounds__(256) void k_spmv(const float* __restrict__ L, const int* __restrict__ cnt,
                                              const int* __restrict__ nb, const float* __restrict__ wg,
                                              const float* __restrict__ x, float* __restrict__ y){
  int i = blockIdx.x*256 + threadIdx.x;
  if (i < NN){
    float acc = L[(size_t)i*NN + i] * x[i];
    int c = min(cnt[i], CAP);
    for (int t = 0; t < c; ++t) acc -= wg[i*CAP+t] * x[nb[i*CAP+t]];
    y[i] = acc;
  }
}

// Y[i,:] = (L X)[i,:] with L sparse, X dense  (L2 = L*L, L3 = L*L2)
__global__ __launch_bounds__(256) void k_srow(const float* __restrict__ L, const int* __restrict__ cnt,
                                              const int* __restrict__ nb, const float* __restrict__ wg,
                                              const float* __restrict__ X, float* __restrict__ Y){
  int i = blockIdx.x;
  __shared__ int   snb[CAP];
  __shared__ float swt[CAP];
  __shared__ float sdiag;
  int c = min(cnt[i], CAP);
  if ((int)threadIdx.x < c){ snb[threadIdx.x] = nb[i*CAP+threadIdx.x]; swt[threadIdx.x] = wg[i*CAP+threadIdx.x]; }
  if (threadIdx.x == 0) sdiag = L[(size_t)i*NN + i];
  __syncthreads();
  for (int j = threadIdx.x; j < NN; j += 256){
    float acc = sdiag * X[(size_t)i*NN + j];
    for (int t = 0; t < c; ++t) acc -= swt[t] * X[(size_t)snb[t]*NN + j];
    Y[(size_t)i*NN + j] = acc;
  }
}

// beta_{k,e} = sum_p dc_{p,e} * a[p+k+1]
__global__ __launch_bounds__(256) void k_beta(const int* __restrict__ edges, const float* __restrict__ cb,
                                              const float* __restrict__ a, float* __restrict__ bt){
  int e = blockIdx.x*256 + threadIdx.x;
  if (e < EE){
    int n = edges[2*e], m = edges[2*e+1];
    float dc0 = cb[n] - cb[m];
    float dc1 = cb[NN+n]   - cb[NN+m];
    float dc2 = cb[2*NN+n] - cb[2*NN+m];
    float dc3 = cb[3*NN+n] - cb[3*NN+m];
    float a1 = a[1], a2 = a[2], a3 = a[3], a4 = a[4];
    bt[e]        = dc0*a1 + dc1*a2 + dc2*a3 + dc3*a4;
    bt[EE+e]     = dc0*a2 + dc1*a3 + dc2*a4;
    bt[2*EE+e]   = dc0*a3 + dc1*a4;
    bt[3*EE+e]   = dc0*a4;
  }
}

// Ht[e,:] = H[:,e] = b0*u_e + b1*L u_e + b2*L2 u_e + b3*L3 u_e   (L^k symmetric -> row reads)
__global__ __launch_bounds__(256) void k_hbuild(const int* __restrict__ edges, const float* __restrict__ bt,
                                                const float* __restrict__ L, const float* __restrict__ L2,
                                                const float* __restrict__ L3, float* __restrict__ Ht){
  int e = blockIdx.x;
  int n = edges[2*e], m = edges[2*e+1];
  float b0 = bt[e], b1 = bt[EE+e], b2 = bt[2*EE+e], b3 = bt[3*EE+e];
  const float* Ln  = L  + (size_t)n*NN; const float* Lm  = L  + (size_t)m*NN;
  const float* L2n = L2 + (size_t)n*NN; const float* L2m = L2 + (size_t)m*NN;
  const float* L3n = L3 + (size_t)n*NN; const float* L3m = L3 + (size_t)m*NN;
  float* He = Ht + (size_t)e*NN;
  for (int j = threadIdx.x; j < NN; j += 256){
    float v = b1*(Ln[j]-Lm[j]) + b2*(L2n[j]-L2m[j]) + b3*(L3n[j]-L3m[j]);
    if (j == n) v += b0;
    if (j == m) v -= b0;
    He[j] = v;
  }
}

__device__ __forceinline__ void tri_decode(int p, int& ti, int& tj){
  ti = (int)((sqrtf(8.f*p + 1.f) - 1.f)*0.5f);
  while ((ti+1)*(ti+2)/2 <= p) ti++;
  while (ti*(ti+1)/2 > p) ti--;
  tj = p - ti*(ti+1)/2;
}

// Spart[z][p] = (Ht^T diag(sg) Ht) 64x64 tile (ti,tj), K-chunk z. f32 loads, f64 LDS + acc.
__global__ __launch_bounds__(256,2) void k_sgemm2(const float* __restrict__ Ht, const float* __restrict__ sg,
                                                  double* __restrict__ Spart){
  int p = blockIdx.x, z = blockIdx.y;
  int ti, tj; tri_decode(p, ti, tj);
  int i0 = ti*64, j0 = tj*64;
  __shared__ double As[32][66];
  __shared__ double Bs[32][66];
  int tid = threadIdx.x;
  int tx = tid & 15, ty = tid >> 4;
  double acc[4][4] = {};
  int kbase = z*(EE/KSPLIT);
  for (int k0 = kbase; k0 < kbase + EE/KSPLIT; k0 += 32){
#pragma unroll
    for (int l = 0; l < 2; ++l){
      int s = tid + 256*l;
      int kk = s >> 4, g = s & 15;
      const float* row = Ht + (size_t)(k0+kk)*NN;
      float4 va = *(const float4*)(row + i0 + g*4);
      float4 vb = *(const float4*)(row + j0 + g*4);
      double sgd = (double)sg[k0+kk];
      As[kk][g*4+0] = (double)va.x; As[kk][g*4+1] = (double)va.y;
      As[kk][g*4+2] = (double)va.z; As[kk][g*4+3] = (double)va.w;
      Bs[kk][g*4+0] = (double)vb.x*sgd; Bs[kk][g*4+1] = (double)vb.y*sgd;
      Bs[kk][g*4+2] = (double)vb.z*sgd; Bs[kk][g*4+3] = (double)vb.w*sgd;
    }
    __syncthreads();
#pragma unroll
    for (int kk = 0; kk < 32; ++kk){
      double av[4], bv[4];
#pragma unroll
      for (int q = 0; q < 4; ++q){ av[q] = As[kk][tx*4+q]; bv[q] = Bs[kk][ty*4+q]; }
#pragma unroll
      for (int r = 0; r < 4; ++r)
#pragma unroll
        for (int c = 0; c < 4; ++c)
          acc[r][c] += av[r]*bv[c];
    }
    __syncthreads();
  }
  double* out = Spart + ((size_t)z*NTILE + p)*4096;
#pragma unroll
  for (int r = 0; r < 4; ++r)
#pragma unroll
    for (int c = 0; c < 4; ++c)
      out[(tx*4+r)*64 + ty*4+c] = acc[r][c];
}

// Sd tile(ti,tj) = sum_z Spart + Cw  (lower tiles; diag tiles full square)
__global__ __launch_bounds__(256) void k_sreduce(const double* __restrict__ Spart, const float* __restrict__ Cw,
                                                 double* __restrict__ Sd){
  int p = blockIdx.x;
  int ti, tj; tri_decode(p, ti, tj);
  int tid = threadIdx.x;
  for (int idx = tid; idx < 4096; idx += 256){
    int r = idx >> 6, c = idx & 63;
    size_t gi = ti*64 + r, gj = tj*64 + c;
    double v = (double)Cw[gi*NN + gj];
#pragma unroll
    for (int z = 0; z < KSPLIT; ++z)
      v += Spart[((size_t)z*NTILE + p)*4096 + idx];
    Sd[gi*NN + gj] = v;
  }
}

// r = y - sum_p a_p c_p  (f64 out)
__global__ __launch_bounds__(256) void k_rvec(const float* __restrict__ y, const float* __restrict__ cb,
                                              const float* __restrict__ a, double* __restrict__ rz){
  int i = blockIdx.x*256 + threadIdx.x;
  if (i < NN){
    double acc = (double)y[i];
    for (int p = 0; p < 5; ++p) acc -= (double)a[p]*(double)cb[p*NN + i];
    rz[i] = acc;
  }
}

// ---------------- persistent LDL^T + solve kernel ----------------
// Factored diag tiles: lower=L(unit,divided), diag=d, upper=unit L^T. grd[i]=1/d_i.
__global__ __launch_bounds__(256,2) void k_solver(double* __restrict__ Sd, double* __restrict__ rz,
                                                  double* __restrict__ grd, int* __restrict__ bar,
                                                  int* __restrict__ go){
  __shared__ double T[BD][BD+1];
  __shared__ double R[BD][BD+1];
  __shared__ double dsh[BD];
  __shared__ double ps[BD][5];
  int bid = blockIdx.x, tid = threadIdx.x;
  int ep = 0;

  // slot barrier: per-block release slot, block0 aggregates, release "go"
  auto GBAR = [&](){
    __syncthreads();
    ep++;
    if (bid == 0){
      if (tid >= 1 && tid < GRIDN){
        while (__hip_atomic_load(&bar[tid*16], __ATOMIC_ACQUIRE, __HIP_MEMORY_SCOPE_AGENT) < ep)
          __builtin_amdgcn_s_sleep(8);
      }
      __syncthreads();
      if (tid == 0) __hip_atomic_store(go, ep, __ATOMIC_RELEASE, __HIP_MEMORY_SCOPE_AGENT);
    } else {
      if (tid == 0){
        __hip_atomic_store(&bar[bid*16], ep, __ATOMIC_RELEASE, __HIP_MEMORY_SCOPE_AGENT);
        while (__hip_atomic_load(go, __ATOMIC_ACQUIRE, __HIP_MEMORY_SCOPE_AGENT) < ep)
          __builtin_amdgcn_s_sleep(8);
      }
      __syncthreads();
    }
  };

  // factor T (in LDS) at offset off0; write L/d/L^T + grd. Leaves dsh = 1/d.
  auto FACTOR_WB = [&](int off0){
    __syncthreads();
    for (int j = 0; j < BD; ++j){
      double dj = T[j][j];
      int fi = tid & 63, cg = tid >> 6;
      if (fi > j){
        double l = T[j][fi]/dj;
        for (int c = j+1+cg; c < BD; c += 4) T[fi][c] -= l*T[j][c];
      }
      __syncthreads();
    }
    if (tid < BD) dsh[tid] = 1.0 / T[tid][tid];
    __syncthreads();
    for (int idx = tid; idx < BD*BD; idx += 256){
      int r = idx >> 6, c = idx & 63;
      double v = (r == c) ? T[r][r] : (r > c ? T[r][c]*dsh[c] : T[r][c]*dsh[r]);
      Sd[(size_t)(off0+r)*NN + off0 + c] = v;
    }
    if (tid < BD) grd[off0+tid] = dsh[tid];
  };

  // ================== factorization ==================
  if (bid == 0){
    for (int idx = tid; idx < BD*BD; idx += 256){
      int r = idx >> 6, c = idx & 63;
      T[r][c] = Sd[(size_t)r*NN + c];
    }
    FACTOR_WB(0);
  }
  GBAR();

  for (int t = 0; t < NB-1; ++t){
    int off = t*BD, off2 = off + BD;
    int nt = NB-1-t;
    // ---- panel phase: block bid handles rows off2+bid*64
    if (bid < nt){
      for (int idx = tid; idx < BD*BD; idx += 256){
        int r = idx >> 6, c = idx & 63;
        T[r][c] = Sd[(size_t)(off+r)*NN + off + c];
      }
      if (tid < BD) dsh[tid] = grd[off+tid];
      __syncthreads();
      int r0 = off2 + bid*BD;
      for (int idx = tid; idx < BD*BD; idx += 256){
        int r = idx >> 6, c = idx & 63;
        R[r][c] = Sd[(size_t)(r0+r)*NN + off + c];
      }
      __syncthreads();
      // chunked trsm: u L11^T = A, u kept undivided in R
      for (int c0 = 0; c0 < BD; c0 += 16){
        if (tid < BD){
          for (int jj = 0; jj < 16; ++jj){
            int j = c0 + jj;
            double acc = R[tid][j];
            for (int k = 0; k < jj; ++k) acc -= R[tid][c0+k]*T[j][c0+k];
            R[tid][j] = acc;
          }
        }
        __syncthreads();
        if (c0 + 16 < BD){
          int r = tid & 63, jg = tid >> 6;
          for (int j = c0+16+jg; j < BD; j += 4){
            double acc = R[r][j];
#pragma unroll
            for (int k = 0; k < 16; ++k) acc -= R[r][c0+k]*T[j][c0+k];
            R[r][j] = acc;
          }
          __syncthreads();
        }
      }
      for (int idx = tid; idx < BD*BD; idx += 256){
        int r = idx >> 6, c = idx & 63;
        Sd[(size_t)(r0+r)*NN + off + c] = R[r][c]*dsh[c];
      }
    }
    GBAR();
    // ---- trailing phase
    int tx = tid & 15, ty = tid >> 4;
    if (bid == 0){
      // reuse LDS: R = undivided u rows (off2 chunk), dsh = 1/d.  PDP^T = sum_k u_r u_c / d_k
      double acc[4][4] = {};
      for (int k = 0; k < BD; ++k){
        double w = dsh[k];
        double av[4], bv[4];
#pragma unroll
        for (int q = 0; q < 4; ++q){ av[q] = R[tx*4+q][k]; bv[q] = R[ty*4+q][k]*w; }
#pragma unroll
        for (int r = 0; r < 4; ++r)
#pragma unroll
          for (int c = 0; c < 4; ++c)
            acc[r][c] += av[r]*bv[c];
      }
      __syncthreads();
#pragma unroll
      for (int r = 0; r < 4; ++r)
#pragma unroll
        for (int c = 0; c < 4; ++c)
          T[tx*4+r][ty*4+c] = Sd[(size_t)(off2+tx*4+r)*NN + off2 + ty*4+c] - acc[r][c];
      FACTOR_WB(off2);
    } else {
      int m = NB-1-t;
      int total = m*(m+1)/2;
      if (tid < BD) dsh[tid] = Sd[(size_t)(off+tid)*NN + off + tid];   // d values
      __syncthreads();
      for (int q = bid; q < total; q += GRIDN-1){
        int ii, jj; tri_decode(q, ii, jj);
        int I = off2 + ii*BD, J = off2 + jj*BD;
        for (int idx = tid; idx < BD*BD; idx += 256){
          int r = idx >> 6, c = idx & 63;
          T[r][c] = Sd[(size_t)(I+r)*NN + off + c];                 // P_I
          R[r][c] = Sd[(size_t)(J+r)*NN + off + c] * dsh[c];        // P_J * d
        }
        __syncthreads();
        double acc[4][4] = {};
        for (int k = 0; k < BD; ++k){
          double av[4], bv[4];
#pragma unroll
          for (int q2 = 0; q2 < 4; ++q2){ av[q2] = T[tx*4+q2][k]; bv[q2] = R[ty*4+q2][k]; }
#pragma unroll
          for (int r = 0; r < 4; ++r)
#pragma unroll
            for (int c = 0; c < 4; ++c)
              acc[r][c] += av[r]*bv[c];
        }
#pragma unroll
        for (int r = 0; r < 4; ++r)
#pragma unroll
          for (int c = 0; c < 4; ++c)
            Sd[(size_t)(I+tx*4+r)*NN + J + ty*4+c] -= acc[r][c];
        __syncthreads();
      }
    }
    GBAR();
  }

  // ================== forward solve: L u = r ==================
  for (int t = 0; t < NB; ++t){
    int off = t*BD;
    if (bid == 0){
      for (int idx = tid; idx < BD*BD; idx += 256){
        int r = idx >> 6, c = idx & 63;
        T[r][c] = Sd[(size_t)(off+r)*NN + off + c];
      }
      __syncthreads();
      if (tid < 64){
        double x = rz[off + tid];
        for (int j = 0; j < BD-1; ++j){
          double xj = __shfl(x, j, 64);
          if (tid > j) x -= T[j][tid]*xj;    // upper = unit L^T
        }
        rz[off + tid] = x;
      }
      __syncthreads();
    }
    GBAR();   // publish z_t
    if (tid < BD) dsh[tid] = rz[off + tid];
    __syncthreads();
    int i0 = (bid == 0) ? off + BD : off + 2*BD + (bid-1)*BD;
    if ((bid == 0 ? (t < NB-1) : (i0 < NN))){
      for (int idx = tid; idx < BD*BD; idx += 256){
        int r = idx >> 6, c = idx & 63;
        R[r][c] = Sd[(size_t)(i0+r)*NN + off + c];
      }
      __syncthreads();
      int r = tid & 63, qg = tid >> 6;
      double acc = 0.0;
#pragma unroll
      for (int k = 0; k < 16; ++k) acc += R[r][qg*16+k]*dsh[qg*16+k];
      ps[r][qg] = acc;
      __syncthreads();
      if (tid < BD) rz[i0+tid] -= ps[tid][0]+ps[tid][1]+ps[tid][2]+ps[tid][3];
      __syncthreads();
    }
  }

  // ================== diagonal: w = u / d ==================
  if (bid < 4){
    int i = bid*256 + tid;
    rz[i] *= grd[i];
  }
  GBAR();

  // ================== backward solve: L^T z = w ==================
  for (int t = NB-1; t >= 0; --t){
    int off = t*BD;
    if (bid == 0){
      for (int idx = tid; idx < BD*BD; idx += 256){
        int r = idx >> 6, c = idx & 63;
        T[r][c] = Sd[(size_t)(off+r)*NN + off + c];
      }
      __syncthreads();
      if (tid < 64){
        double x = rz[off + tid];
        for (int j = BD-1; j >= 1; --j){
          double xj = __shfl(x, j, 64);
          if (tid < j) x -= T[j][tid]*xj;    // lower = unit L
        }
        rz[off + tid] = x;
      }
      __syncthreads();
    }
    GBAR();   // publish x_t
    if (tid < BD) dsh[tid] = rz[off + tid];
    __syncthreads();
    int c0 = (bid == 0) ? off - BD : (bid-1)*BD;
    if ((bid == 0 ? (t > 0) : (c0 < off - BD))){
      for (int idx = tid; idx < BD*BD; idx += 256){
        int r = idx >> 6, c = idx & 63;
        R[r][c] = Sd[(size_t)(off+r)*NN + c0 + c];    // L21 panel rows (j, col chunk)
      }
      __syncthreads();
      int c = tid & 63, qg = tid >> 6;
      double acc = 0.0;
#pragma unroll
      for (int j = 0; j < 16; ++j) acc += R[qg*16+j][c]*dsh[qg*16+j];
      ps[c][qg] = acc;
      __syncthreads();
      if (tid < BD) rz[c0+tid] -= ps[tid][0]+ps[tid][1]+ps[tid][2]+ps[tid][3];
      __syncthreads();
    }
  }
}

// s_out = relu(s + sigma .* (Ht z))
__global__ __launch_bounds__(256) void k_snew(const float* __restrict__ Ht, const float* __restrict__ sv,
                                              const float* __restrict__ sg, const double* __restrict__ z,
                                              float* __restrict__ out){
  int e = blockIdx.x*4 + (threadIdx.x >> 6);
  int lane = threadIdx.x & 63;
  const float* He = Ht + (size_t)e*NN;
  double acc = 0.0;
  for (int j = lane; j < NN; j += 64) acc += (double)He[j]*z[j];
  acc = waveReduceD(acc);
  if (lane == 0){
    double val = (double)sv[e] + (double)sg[e]*acc;
    out[e] = fmaxf((float)val, 0.0f);
  }
}

extern "C" void kernel_launch(void* const* d_in, const int* in_sizes, int n_in,
                              void* d_out, int out_size, void* d_ws, size_t ws_size,
                              hipStream_t stream){
  const float* q   = (const float*)d_in[0];
  const float* y   = (const float*)d_in[1];
  const float* F   = (const float*)d_in[2];
  // d_in[3] = B (incidence) — structure carried by edges
  const int*   edges = (const int*)d_in[4];
  const float* Cu  = (const float*)d_in[5];
  const float* Cw  = (const float*)d_in[6];
  const float* s0  = (const float*)d_in[7];
  const float* Sg0 = (const float*)d_in[8];
  const float* a   = (const float*)d_in[9];
  float* out = (float*)d_out;

  double* Sd    = (double*)d_ws;                       // 8 MB
  double* Spart = Sd + (size_t)NN*NN;                  // 17.8 MB
  double* rz    = Spart + (size_t)KSPLIT*NTILE*4096;
  double* grd   = rz + NN;
  float* w = (float*)(grd + NN);
  float* L  = w; w += (size_t)NN*NN;
  float* L2 = w; w += (size_t)NN*NN;
  float* L3 = w; w += (size_t)NN*NN;
  float* Ht = w; w += (size_t)EE*NN;
  float* cb = w; w += 5*NN;
  float* sv = w; w += EE;
  float* sg = w; w += EE;
  float* bt = w; w += 4*EE;
  float* wg = w; w += (size_t)NN*CAP;
  int* cnt  = (int*)w; w += NN;
  int* nb   = (int*)w; w += (size_t)NN*CAP;
  int* bar  = (int*)w; w += GRIDN*16 + 64;
  int* go   = bar + GRIDN*16 + 16;

  hipMemsetAsync(L, 0, (size_t)NN*NN*sizeof(float), stream);
  hipMemsetAsync(cnt, 0, NN*sizeof(int), stream);
  hipMemsetAsync(bar, 0, (GRIDN*16 + 64)*sizeof(int), stream);

  k_edge_init<<<EE/256, 256, 0, stream>>>(F, Sg0, Cu, s0, sv, sg);
  k_scatter<<<EE/256, 256, 0, stream>>>(edges, sv, L, cnt, nb, wg);

  hipMemcpyAsync(cb, q, NN*sizeof(float), hipMemcpyDeviceToDevice, stream);
  for (int p = 1; p < 5; ++p)
    k_spmv<<<NN/256, 256, 0, stream>>>(L, cnt, nb, wg, cb + (p-1)*NN, cb + p*NN);

  k_srow<<<NN, 256, 0, stream>>>(L, cnt, nb, wg, L,  L2);
  k_srow<<<NN, 256, 0, stream>>>(L, cnt, nb, wg, L2, L3);

  k_beta<<<EE/256, 256, 0, stream>>>(edges, cb, a, bt);
  k_hbuild<<<EE, 256, 0, stream>>>(edges, bt, L, L2, L3, Ht);

  dim3 gg(NTILE, KSPLIT);
  k_sgemm2<<<gg, 256, 0, stream>>>(Ht, sg, Spart);
  k_sreduce<<<NTILE, 256, 0, stream>>>(Spart, Cw, Sd);

  k_rvec<<<NN/256, 256, 0, stream>>>(y, cb, a, rz);

  k_solver<<<GRIDN, 256, 0, stream>>>(Sd, rz, grd, bar, go);

  k_snew<<<EE/4, 256, 0, stream>>>(Ht, sv, sg, rz, out);
}

// Round 5
// 1634.573 us; speedup vs baseline: 3.7582x; 1.7196x over previous
//
#include <hip/hip_runtime.h>

#define NN 1024
#define EE 4096
#define CAP 64
#define BD 64
#define NB (NN/BD)
#define KSPLIT 4
#define NTILE 136

// flag slots (each *16 ints apart): tile done 0..135; zf 136..151; xf 152..167;
// cntf 168..183; cntb 184..199
#define SL_ZF(t)  (136+(t))
#define SL_XF(t)  (152+(t))
#define SL_CF(t)  (168+(t))
#define SL_CB(t)  (184+(t))
#define NSLOT 200

__device__ __forceinline__ double waveReduceD(double v){
  for (int o = 32; o; o >>= 1) v += __shfl_down(v, o, 64);
  return v;
}

// s_e = F_ee * s0_e ; sigma_e = F_ee^2 * Sigma0_ee + Cu_ee (diagonal structure, values read at runtime)
__global__ __launch_bounds__(256) void k_edge_init(const float* __restrict__ F, const float* __restrict__ Sg0,
                                                   const float* __restrict__ Cu, const float* __restrict__ s0,
                                                   float* __restrict__ sv, float* __restrict__ sg){
  int e = blockIdx.x*256 + threadIdx.x;
  if (e < EE){
    float f = F[(size_t)e*EE + e];
    sv[e] = f * s0[e];
    sg[e] = f*f*Sg0[(size_t)e*EE + e] + Cu[(size_t)e*EE + e];
  }
}

// L = weighted Laplacian from edges; also adjacency lists
__global__ __launch_bounds__(256) void k_scatter(const int* __restrict__ edges, const float* __restrict__ sv,
                                                 float* __restrict__ L, int* __restrict__ cnt,
                                                 int* __restrict__ nb, float* __restrict__ wg){
  int e = blockIdx.x*256 + threadIdx.x;
  if (e < EE){
    int n = edges[2*e], m = edges[2*e+1];
    float se = sv[e];
    atomicAdd(&L[(size_t)n*NN + n],  se);
    atomicAdd(&L[(size_t)m*NN + m],  se);
    atomicAdd(&L[(size_t)n*NN + m], -se);
    atomicAdd(&L[(size_t)m*NN + n], -se);
    int p1 = atomicAdd(&cnt[n], 1);
    if (p1 < CAP){ nb[n*CAP+p1] = m; wg[n*CAP+p1] = se; }
    int p2 = atomicAdd(&cnt[m], 1);
    if (p2 < CAP){ nb[m*CAP+p2] = n; wg[m*CAP+p2] = se; }
  }
}

// y = L x (sparse)
__global__ __launch_bounds__(256) void k_spmv(const float* __restrict__ L, const int* __restrict__ cnt,
                                              const int* __restrict__ nb, const float* __restrict__ wg,
                                              const float* __restrict__ x, float* __restrict__ y){
  int i = blockIdx.x*256 + threadIdx.x;
  if (i < NN){
    float acc = L[(size_t)i*NN + i] * x[i];
    int c = min(cnt[i], CAP);
    for (int t = 0; t < c; ++t) acc -= wg[i*CAP+t] * x[nb[i*CAP+t]];
    y[i] = acc;
  }
}

// Y[i,:] = (L X)[i,:] with L sparse, X dense  (L2 = L*L, L3 = L*L2)
__global__ __launch_bounds__(256) void k_srow(const float* __restrict__ L, const int* __restrict__ cnt,
                                              const int* __restrict__ nb, const float* __restrict__ wg,
                                              const float* __restrict__ X, float* __restrict__ Y){
  int i = blockIdx.x;
  __shared__ int   snb[CAP];
  __shared__ float swt[CAP];
  __shared__ float sdiag;
  int c = min(cnt[i], CAP);
  if ((int)threadIdx.x < c){ snb[threadIdx.x] = nb[i*CAP+threadIdx.x]; swt[threadIdx.x] = wg[i*CAP+threadIdx.x]; }
  if (threadIdx.x == 0) sdiag = L[(size_t)i*NN + i];
  __syncthreads();
  for (int j = threadIdx.x; j < NN; j += 256){
    float acc = sdiag * X[(size_t)i*NN + j];
    for (int t = 0; t < c; ++t) acc -= swt[t] * X[(size_t)snb[t]*NN + j];
    Y[(size_t)i*NN + j] = acc;
  }
}

// beta_{k,e} = sum_p dc_{p,e} * a[p+k+1]
__global__ __launch_bounds__(256) void k_beta(const int* __restrict__ edges, const float* __restrict__ cb,
                                              const float* __restrict__ a, float* __restrict__ bt){
  int e = blockIdx.x*256 + threadIdx.x;
  if (e < EE){
    int n = edges[2*e], m = edges[2*e+1];
    float dc0 = cb[n] - cb[m];
    float dc1 = cb[NN+n]   - cb[NN+m];
    float dc2 = cb[2*NN+n] - cb[2*NN+m];
    float dc3 = cb[3*NN+n] - cb[3*NN+m];
    float a1 = a[1], a2 = a[2], a3 = a[3], a4 = a[4];
    bt[e]        = dc0*a1 + dc1*a2 + dc2*a3 + dc3*a4;
    bt[EE+e]     = dc0*a2 + dc1*a3 + dc2*a4;
    bt[2*EE+e]   = dc0*a3 + dc1*a4;
    bt[3*EE+e]   = dc0*a4;
  }
}

// Ht[e,:] = H[:,e] = b0*u_e + b1*L u_e + b2*L2 u_e + b3*L3 u_e   (L^k symmetric -> row reads)
__global__ __launch_bounds__(256) void k_hbuild(const int* __restrict__ edges, const float* __restrict__ bt,
                                                const float* __restrict__ L, const float* __restrict__ L2,
                                                const float* __restrict__ L3, float* __restrict__ Ht){
  int e = blockIdx.x;
  int n = edges[2*e], m = edges[2*e+1];
  float b0 = bt[e], b1 = bt[EE+e], b2 = bt[2*EE+e], b3 = bt[3*EE+e];
  const float* Ln  = L  + (size_t)n*NN; const float* Lm  = L  + (size_t)m*NN;
  const float* L2n = L2 + (size_t)n*NN; const float* L2m = L2 + (size_t)m*NN;
  const float* L3n = L3 + (size_t)n*NN; const float* L3m = L3 + (size_t)m*NN;
  float* He = Ht + (size_t)e*NN;
  for (int j = threadIdx.x; j < NN; j += 256){
    float v = b1*(Ln[j]-Lm[j]) + b2*(L2n[j]-L2m[j]) + b3*(L3n[j]-L3m[j]);
    if (j == n) v += b0;
    if (j == m) v -= b0;
    He[j] = v;
  }
}

__device__ __forceinline__ void tri_decode(int p, int& ti, int& tj){
  ti = (int)((sqrtf(8.f*p + 1.f) - 1.f)*0.5f);
  while ((ti+1)*(ti+2)/2 <= p) ti++;
  while (ti*(ti+1)/2 > p) ti--;
  tj = p - ti*(ti+1)/2;
}

// Spart[z][p] = (Ht^T diag(sg) Ht) 64x64 tile (ti,tj), K-chunk z. f32 loads, f64 LDS + acc.
__global__ __launch_bounds__(256,2) void k_sgemm2(const float* __restrict__ Ht, const float* __restrict__ sg,
                                                  double* __restrict__ Spart){
  int p = blockIdx.x, z = blockIdx.y;
  int ti, tj; tri_decode(p, ti, tj);
  int i0 = ti*64, j0 = tj*64;
  __shared__ double As[32][66];
  __shared__ double Bs[32][66];
  int tid = threadIdx.x;
  int tx = tid & 15, ty = tid >> 4;
  double acc[4][4] = {};
  int kbase = z*(EE/KSPLIT);
  for (int k0 = kbase; k0 < kbase + EE/KSPLIT; k0 += 32){
#pragma unroll
    for (int l = 0; l < 2; ++l){
      int s = tid + 256*l;
      int kk = s >> 4, g = s & 15;
      const float* row = Ht + (size_t)(k0+kk)*NN;
      float4 va = *(const float4*)(row + i0 + g*4);
      float4 vb = *(const float4*)(row + j0 + g*4);
      double sgd = (double)sg[k0+kk];
      As[kk][g*4+0] = (double)va.x; As[kk][g*4+1] = (double)va.y;
      As[kk][g*4+2] = (double)va.z; As[kk][g*4+3] = (double)va.w;
      Bs[kk][g*4+0] = (double)vb.x*sgd; Bs[kk][g*4+1] = (double)vb.y*sgd;
      Bs[kk][g*4+2] = (double)vb.z*sgd; Bs[kk][g*4+3] = (double)vb.w*sgd;
    }
    __syncthreads();
#pragma unroll
    for (int kk = 0; kk < 32; ++kk){
      double av[4], bv[4];
#pragma unroll
      for (int q = 0; q < 4; ++q){ av[q] = As[kk][tx*4+q]; bv[q] = Bs[kk][ty*4+q]; }
#pragma unroll
      for (int r = 0; r < 4; ++r)
#pragma unroll
        for (int c = 0; c < 4; ++c)
          acc[r][c] += av[r]*bv[c];
    }
    __syncthreads();
  }
  double* out = Spart + ((size_t)z*NTILE + p)*4096;
#pragma unroll
  for (int r = 0; r < 4; ++r)
#pragma unroll
    for (int c = 0; c < 4; ++c)
      out[(tx*4+r)*64 + ty*4+c] = acc[r][c];
}

// Sd tile(ti,tj) = sum_z Spart + Cw  (lower tiles; diag tiles full square)
__global__ __launch_bounds__(256) void k_sreduce(const double* __restrict__ Spart, const float* __restrict__ Cw,
                                                 double* __restrict__ Sd){
  int p = blockIdx.x;
  int ti, tj; tri_decode(p, ti, tj);
  int tid = threadIdx.x;
  for (int idx = tid; idx < 4096; idx += 256){
    int r = idx >> 6, c = idx & 63;
    size_t gi = ti*64 + r, gj = tj*64 + c;
    double v = (double)Cw[gi*NN + gj];
#pragma unroll
    for (int z = 0; z < KSPLIT; ++z)
      v += Spart[((size_t)z*NTILE + p)*4096 + idx];
    Sd[gi*NN + gj] = v;
  }
}

// r = y - sum_p a_p c_p  (f64 out)
__global__ __launch_bounds__(256) void k_rvec(const float* __restrict__ y, const float* __restrict__ cb,
                                              const float* __restrict__ a, double* __restrict__ rz){
  int i = blockIdx.x*256 + threadIdx.x;
  if (i < NN){
    double acc = (double)y[i];
    for (int p = 0; p < 5; ++p) acc -= (double)a[p]*(double)cb[p*NN + i];
    rz[i] = acc;
  }
}

// =============== DAG-scheduled LDL^T factorization + solve, ZERO grid barriers ===============
// Tile (I,J) (I>=J, 64x64) owned by block p=I(I+1)/2+J. Diag tiles store L(unit,divided) lower,
// d on diag, unit L^T upper. Panels stored divided. grd=1/d, dvals=d.
// Block NTILE runs the serial triangular solves; panel owners contribute matvecs via f64 atomics.
__global__ __launch_bounds__(256) void k_fact(double* __restrict__ Sd, double* __restrict__ rz,
                                              double* __restrict__ grd, double* __restrict__ dvals,
                                              int* __restrict__ fl){
  __shared__ double T[BD][BD+1];
  __shared__ double R[BD][BD+1];
  __shared__ double dsh[BD];
  __shared__ double zsh[BD];
  __shared__ double ps[BD][5];
  int bid = blockIdx.x, tid = threadIdx.x;
  int tx = tid & 15, ty = tid >> 4;

  auto wait_slot = [&](int slot){
    if (tid == 0){
      int it = 0;
      while (__hip_atomic_load(&fl[slot*16], __ATOMIC_ACQUIRE, __HIP_MEMORY_SCOPE_AGENT) == 0 && it < 400000){
        __builtin_amdgcn_s_sleep(32); ++it;
      }
    }
    __syncthreads();
  };
  auto wait_cnt = [&](int slot, int target){
    if (tid == 0){
      int it = 0;
      while (__hip_atomic_load(&fl[slot*16], __ATOMIC_ACQUIRE, __HIP_MEMORY_SCOPE_AGENT) < target && it < 400000){
        __builtin_amdgcn_s_sleep(32); ++it;
      }
    }
    __syncthreads();
  };
  auto set_slot = [&](int slot){
    __syncthreads();
    if (tid == 0) __hip_atomic_store(&fl[slot*16], 1, __ATOMIC_RELEASE, __HIP_MEMORY_SCOPE_AGENT);
  };

  if (bid < NTILE){
    int I, J; tri_decode(bid, I, J);
    int i64 = I*64, j64 = J*64;
    // own tile -> registers (via coalesced LDS staging)
    double acc[4][4];
    for (int idx = tid; idx < 4096; idx += 256){
      int r = idx >> 6, c = idx & 63;
      R[r][c] = Sd[(size_t)(i64+r)*NN + j64 + c];
    }
    __syncthreads();
#pragma unroll
    for (int q = 0; q < 4; ++q)
#pragma unroll
      for (int p2 = 0; p2 < 4; ++p2) acc[q][p2] = R[tx*4+q][ty*4+p2];
    __syncthreads();

    // trailing updates: acc -= P(I,t) * D(t) * P(J,t)^T   for t < J
    for (int t = 0; t < J; ++t){
      int t64 = t*64;
      wait_slot(I*(I+1)/2 + t);                 // panel (I,t) done (implies diag t, dvals via transitivity)
      if (I != J) wait_slot(J*(J+1)/2 + t);     // panel (J,t) done
      for (int idx = tid; idx < 4096; idx += 256){
        int r = idx >> 6, c = idx & 63;
        T[r][c] = Sd[(size_t)(i64+r)*NN + t64 + c];
        R[r][c] = Sd[(size_t)(j64+r)*NN + t64 + c] * dvals[t64+c];
      }
      __syncthreads();
      for (int k = 0; k < 64; ++k){
        double av[4], bv[4];
#pragma unroll
        for (int q = 0; q < 4; ++q){ av[q] = T[tx*4+q][k]; bv[q] = R[ty*4+q][k]; }
#pragma unroll
        for (int r = 0; r < 4; ++r)
#pragma unroll
          for (int c = 0; c < 4; ++c)
            acc[r][c] -= av[r]*bv[c];
      }
      __syncthreads();
    }

    if (I == J){
      // materialize into T, factor (validated r4 routine), write back + d
#pragma unroll
      for (int q = 0; q < 4; ++q)
#pragma unroll
        for (int p2 = 0; p2 < 4; ++p2) T[tx*4+q][ty*4+p2] = acc[q][p2];
      __syncthreads();
      for (int j = 0; j < BD; ++j){
        double dj = T[j][j];
        int fi = tid & 63, cg = tid >> 6;
        if (fi > j){
          double l = T[j][fi]/dj;
          for (int c = j+1+cg; c < BD; c += 4) T[fi][c] -= l*T[j][c];
        }
        __syncthreads();
      }
      if (tid < BD) dsh[tid] = 1.0 / T[tid][tid];
      __syncthreads();
      for (int idx = tid; idx < BD*BD; idx += 256){
        int r = idx >> 6, c = idx & 63;
        double v = (r == c) ? T[r][r] : (r > c ? T[r][c]*dsh[c] : T[r][c]*dsh[r]);
        Sd[(size_t)(i64+r)*NN + i64 + c] = v;
      }
      if (tid < BD){ grd[i64+tid] = dsh[tid]; dvals[i64+tid] = T[tid][tid]; }
      set_slot(bid);
    } else {
      // materialize into R, trsm vs factored diag J (validated r4 routine), divide, write
#pragma unroll
      for (int q = 0; q < 4; ++q)
#pragma unroll
        for (int p2 = 0; p2 < 4; ++p2) R[tx*4+q][ty*4+p2] = acc[q][p2];
      wait_slot(J*(J+1)/2 + J);                 // diag (J,J) factored
      for (int idx = tid; idx < 4096; idx += 256){
        int r = idx >> 6, c = idx & 63;
        T[r][c] = Sd[(size_t)(j64+r)*NN + j64 + c];
      }
      if (tid < BD) dsh[tid] = grd[j64+tid];
      __syncthreads();
      for (int c0 = 0; c0 < BD; c0 += 16){
        if (tid < BD){
          for (int jj = 0; jj < 16; ++jj){
            int j = c0 + jj;
            double a2 = R[tid][j];
            for (int k = 0; k < jj; ++k) a2 -= R[tid][c0+k]*T[j][c0+k];
            R[tid][j] = a2;
          }
        }
        __syncthreads();
        if (c0 + 16 < BD){
          int r2 = tid & 63, jg = tid >> 6;
          for (int j = c0+16+jg; j < BD; j += 4){
            double a2 = R[r2][j];
#pragma unroll
            for (int k = 0; k < 16; ++k) a2 -= R[r2][c0+k]*T[j][c0+k];
            R[r2][j] = a2;
          }
        }
        __syncthreads();
      }
      for (int idx = tid; idx < 4096; idx += 256){
        int r = idx >> 6, c = idx & 63;
        Sd[(size_t)(i64+r)*NN + j64 + c] = R[r][c]*dsh[c];
      }
      set_slot(bid);

      // ---- forward-solve contribution: rz[I] -= P(I,J) z_J
      wait_slot(SL_ZF(J));
      if (tid < BD) zsh[tid] = rz[j64+tid];
      __syncthreads();
      {
        int r = tid & 63, qg = tid >> 6;
        double a2 = 0.0;
#pragma unroll
        for (int k = 0; k < 16; ++k){ int c = qg*16+k; a2 += R[r][c]*dsh[c]*zsh[c]; }
        ps[r][qg] = a2;
      }
      __syncthreads();
      if (tid < BD){
        double v = ps[tid][0]+ps[tid][1]+ps[tid][2]+ps[tid][3];
        __hip_atomic_fetch_add(&rz[i64+tid], -v, __ATOMIC_RELAXED, __HIP_MEMORY_SCOPE_AGENT);
      }
      __syncthreads();
      if (tid == 0) __hip_atomic_fetch_add(&fl[SL_CF(I)*16], 1, __ATOMIC_RELEASE, __HIP_MEMORY_SCOPE_AGENT);

      // ---- backward-solve contribution: rz[J] -= P(I,J)^T x_I
      wait_slot(SL_XF(I));
      if (tid < BD) zsh[tid] = rz[i64+tid];
      __syncthreads();
      {
        int c = tid & 63, qg = tid >> 6;
        double a2 = 0.0;
#pragma unroll
        for (int k = 0; k < 16; ++k){ int r = qg*16+k; a2 += R[r][c]*zsh[r]; }
        ps[c][qg] = a2;
      }
      __syncthreads();
      if (tid < BD){
        double v = (ps[tid][0]+ps[tid][1]+ps[tid][2]+ps[tid][3])*dsh[tid];
        __hip_atomic_fetch_add(&rz[j64+tid], -v, __ATOMIC_RELAXED, __HIP_MEMORY_SCOPE_AGENT);
      }
      __syncthreads();
      if (tid == 0) __hip_atomic_fetch_add(&fl[SL_CB(J)*16], 1, __ATOMIC_RELEASE, __HIP_MEMORY_SCOPE_AGENT);
    }
  } else {
    // =============== solver block ===============
    // forward: z_t = unitL^{-1}(r_t - contributions)
    for (int t = 0; t < NB; ++t){
      wait_cnt(SL_CF(t)*1, t);  // placeholder; fixed below
      // (the actual slot math is SL_CF(t); wait_cnt takes slot index)
      // -- re-do properly:
      // NOTE: wait_cnt(SL_CF(t), t) is what we want; call made above with slot SL_CF(t)*1 == SL_CF(t).
      wait_slot(t*(t+1)/2 + t);
      for (int idx = tid; idx < BD*BD; idx += 256){
        int r = idx >> 6, c = idx & 63;
        T[r][c] = Sd[(size_t)(t*64+r)*NN + t*64 + c];
      }
      __syncthreads();
      if (tid < 64){
        double x = rz[t*64 + tid];
        for (int j = 0; j < BD-1; ++j){
          double xj = __shfl(x, j, 64);
          if (tid > j) x -= T[j][tid]*xj;      // upper = unit L^T
        }
        rz[t*64 + tid] = x;
      }
      set_slot(SL_ZF(t));
    }
    // diagonal scale: w = z / d
    for (int i = tid; i < NN; i += 256) rz[i] *= grd[i];
    __syncthreads();
    // backward: L^T x = w
    for (int t = NB-1; t >= 0; --t){
      wait_cnt(SL_CB(t), NB-1-t);
      for (int idx = tid; idx < BD*BD; idx += 256){
        int r = idx >> 6, c = idx & 63;
        T[r][c] = Sd[(size_t)(t*64+r)*NN + t*64 + c];
      }
      __syncthreads();
      if (tid < 64){
        double x = rz[t*64 + tid];
        for (int j = BD-1; j >= 1; --j){
          double xj = __shfl(x, j, 64);
          if (tid < j) x -= T[j][tid]*xj;      // lower = unit L
        }
        rz[t*64 + tid] = x;
      }
      set_slot(SL_XF(t));
    }
  }
}

// s_out = relu(s + sigma .* (Ht z))
__global__ __launch_bounds__(256) void k_snew(const float* __restrict__ Ht, const float* __restrict__ sv,
                                              const float* __restrict__ sg, const double* __restrict__ z,
                                              float* __restrict__ out){
  int e = blockIdx.x*4 + (threadIdx.x >> 6);
  int lane = threadIdx.x & 63;
  const float* He = Ht + (size_t)e*NN;
  double acc = 0.0;
  for (int j = lane; j < NN; j += 64) acc += (double)He[j]*z[j];
  acc = waveReduceD(acc);
  if (lane == 0){
    double val = (double)sv[e] + (double)sg[e]*acc;
    out[e] = fmaxf((float)val, 0.0f);
  }
}

extern "C" void kernel_launch(void* const* d_in, const int* in_sizes, int n_in,
                              void* d_out, int out_size, void* d_ws, size_t ws_size,
                              hipStream_t stream){
  const float* q   = (const float*)d_in[0];
  const float* y   = (const float*)d_in[1];
  const float* F   = (const float*)d_in[2];
  // d_in[3] = B (incidence) — structure carried by edges
  const int*   edges = (const int*)d_in[4];
  const float* Cu  = (const float*)d_in[5];
  const float* Cw  = (const float*)d_in[6];
  const float* s0  = (const float*)d_in[7];
  const float* Sg0 = (const float*)d_in[8];
  const float* a   = (const float*)d_in[9];
  float* out = (float*)d_out;

  double* Sd    = (double*)d_ws;                       // 8 MB
  double* Spart = Sd + (size_t)NN*NN;                  // 17.8 MB
  double* rz    = Spart + (size_t)KSPLIT*NTILE*4096;
  double* grd   = rz + NN;
  double* dvals = grd + NN;
  float* w = (float*)(dvals + NN);
  float* L  = w; w += (size_t)NN*NN;
  float* L2 = w; w += (size_t)NN*NN;
  float* L3 = w; w += (size_t)NN*NN;
  float* Ht = w; w += (size_t)EE*NN;
  float* cb = w; w += 5*NN;
  float* sv = w; w += EE;
  float* sg = w; w += EE;
  float* bt = w; w += 4*EE;
  float* wg = w; w += (size_t)NN*CAP;
  int* cnt  = (int*)w; w += NN;
  int* nb   = (int*)w; w += (size_t)NN*CAP;
  int* fl   = (int*)w; w += NSLOT*16;

  hipMemsetAsync(L, 0, (size_t)NN*NN*sizeof(float), stream);
  hipMemsetAsync(cnt, 0, NN*sizeof(int), stream);
  hipMemsetAsync(fl, 0, NSLOT*16*sizeof(int), stream);

  k_edge_init<<<EE/256, 256, 0, stream>>>(F, Sg0, Cu, s0, sv, sg);
  k_scatter<<<EE/256, 256, 0, stream>>>(edges, sv, L, cnt, nb, wg);

  hipMemcpyAsync(cb, q, NN*sizeof(float), hipMemcpyDeviceToDevice, stream);
  for (int p = 1; p < 5; ++p)
    k_spmv<<<NN/256, 256, 0, stream>>>(L, cnt, nb, wg, cb + (p-1)*NN, cb + p*NN);

  k_srow<<<NN, 256, 0, stream>>>(L, cnt, nb, wg, L,  L2);
  k_srow<<<NN, 256, 0, stream>>>(L, cnt, nb, wg, L2, L3);

  k_beta<<<EE/256, 256, 0, stream>>>(edges, cb, a, bt);
  k_hbuild<<<EE, 256, 0, stream>>>(edges, bt, L, L2, L3, Ht);

  dim3 gg(NTILE, KSPLIT);
  k_sgemm2<<<gg, 256, 0, stream>>>(Ht, sg, Spart);
  k_sreduce<<<NTILE, 256, 0, stream>>>(Spart, Cw, Sd);

  k_rvec<<<NN/256, 256, 0, stream>>>(y, cb, a, rz);

  k_fact<<<NTILE+1, 256, 0, stream>>>(Sd, rz, grd, dvals, fl);

  k_snew<<<EE/4, 256, 0, stream>>>(Ht, sv, sg, rz, out);
}

// Round 6
// 1573.194 us; speedup vs baseline: 3.9048x; 1.0390x over previous
//
#include <hip/hip_runtime.h>

#define NN 1024
#define EE 4096
#define CAP 64
#define BD 64
#define NB (NN/BD)
#define KSPLIT 4
#define NTILE 136
#define NSLOT 200

__device__ __forceinline__ double waveReduceD(double v){
  for (int o = 32; o; o >>= 1) v += __shfl_down(v, o, 64);
  return v;
}

// s_e = F_ee * s0_e ; sigma_e = F_ee^2 * Sigma0_ee + Cu_ee (diagonal structure, values read at runtime)
__global__ __launch_bounds__(256) void k_edge_init(const float* __restrict__ F, const float* __restrict__ Sg0,
                                                   const float* __restrict__ Cu, const float* __restrict__ s0,
                                                   float* __restrict__ sv, float* __restrict__ sg){
  int e = blockIdx.x*256 + threadIdx.x;
  if (e < EE){
    float f = F[(size_t)e*EE + e];
    sv[e] = f * s0[e];
    sg[e] = f*f*Sg0[(size_t)e*EE + e] + Cu[(size_t)e*EE + e];
  }
}

// L = weighted Laplacian from edges; also adjacency lists
__global__ __launch_bounds__(256) void k_scatter(const int* __restrict__ edges, const float* __restrict__ sv,
                                                 float* __restrict__ L, int* __restrict__ cnt,
                                                 int* __restrict__ nb, float* __restrict__ wg){
  int e = blockIdx.x*256 + threadIdx.x;
  if (e < EE){
    int n = edges[2*e], m = edges[2*e+1];
    float se = sv[e];
    atomicAdd(&L[(size_t)n*NN + n],  se);
    atomicAdd(&L[(size_t)m*NN + m],  se);
    atomicAdd(&L[(size_t)n*NN + m], -se);
    atomicAdd(&L[(size_t)m*NN + n], -se);
    int p1 = atomicAdd(&cnt[n], 1);
    if (p1 < CAP){ nb[n*CAP+p1] = m; wg[n*CAP+p1] = se; }
    int p2 = atomicAdd(&cnt[m], 1);
    if (p2 < CAP){ nb[m*CAP+p2] = n; wg[m*CAP+p2] = se; }
  }
}

// y = L x (sparse)
__global__ __launch_bounds__(256) void k_spmv(const float* __restrict__ L, const int* __restrict__ cnt,
                                              const int* __restrict__ nb, const float* __restrict__ wg,
                                              const float* __restrict__ x, float* __restrict__ y){
  int i = blockIdx.x*256 + threadIdx.x;
  if (i < NN){
    float acc = L[(size_t)i*NN + i] * x[i];
    int c = min(cnt[i], CAP);
    for (int t = 0; t < c; ++t) acc -= wg[i*CAP+t] * x[nb[i*CAP+t]];
    y[i] = acc;
  }
}

// Y[i,:] = (L X)[i,:] with L sparse, X dense  (L2 = L*L, L3 = L*L2)
__global__ __launch_bounds__(256) void k_srow(const float* __restrict__ L, const int* __restrict__ cnt,
                                              const int* __restrict__ nb, const float* __restrict__ wg,
                                              const float* __restrict__ X, float* __restrict__ Y){
  int i = blockIdx.x;
  __shared__ int   snb[CAP];
  __shared__ float swt[CAP];
  __shared__ float sdiag;
  int c = min(cnt[i], CAP);
  if ((int)threadIdx.x < c){ snb[threadIdx.x] = nb[i*CAP+threadIdx.x]; swt[threadIdx.x] = wg[i*CAP+threadIdx.x]; }
  if (threadIdx.x == 0) sdiag = L[(size_t)i*NN + i];
  __syncthreads();
  for (int j = threadIdx.x; j < NN; j += 256){
    float acc = sdiag * X[(size_t)i*NN + j];
    for (int t = 0; t < c; ++t) acc -= swt[t] * X[(size_t)snb[t]*NN + j];
    Y[(size_t)i*NN + j] = acc;
  }
}

// beta_{k,e} = sum_p dc_{p,e} * a[p+k+1]
__global__ __launch_bounds__(256) void k_beta(const int* __restrict__ edges, const float* __restrict__ cb,
                                              const float* __restrict__ a, float* __restrict__ bt){
  int e = blockIdx.x*256 + threadIdx.x;
  if (e < EE){
    int n = edges[2*e], m = edges[2*e+1];
    float dc0 = cb[n] - cb[m];
    float dc1 = cb[NN+n]   - cb[NN+m];
    float dc2 = cb[2*NN+n] - cb[2*NN+m];
    float dc3 = cb[3*NN+n] - cb[3*NN+m];
    float a1 = a[1], a2 = a[2], a3 = a[3], a4 = a[4];
    bt[e]        = dc0*a1 + dc1*a2 + dc2*a3 + dc3*a4;
    bt[EE+e]     = dc0*a2 + dc1*a3 + dc2*a4;
    bt[2*EE+e]   = dc0*a3 + dc1*a4;
    bt[3*EE+e]   = dc0*a4;
  }
}

// Ht[e,:] = H[:,e] = b0*u_e + b1*L u_e + b2*L2 u_e + b3*L3 u_e   (L^k symmetric -> row reads)
__global__ __launch_bounds__(256) void k_hbuild(const int* __restrict__ edges, const float* __restrict__ bt,
                                                const float* __restrict__ L, const float* __restrict__ L2,
                                                const float* __restrict__ L3, float* __restrict__ Ht){
  int e = blockIdx.x;
  int n = edges[2*e], m = edges[2*e+1];
  float b0 = bt[e], b1 = bt[EE+e], b2 = bt[2*EE+e], b3 = bt[3*EE+e];
  const float* Ln  = L  + (size_t)n*NN; const float* Lm  = L  + (size_t)m*NN;
  const float* L2n = L2 + (size_t)n*NN; const float* L2m = L2 + (size_t)m*NN;
  const float* L3n = L3 + (size_t)n*NN; const float* L3m = L3 + (size_t)m*NN;
  float* He = Ht + (size_t)e*NN;
  for (int j = threadIdx.x; j < NN; j += 256){
    float v = b1*(Ln[j]-Lm[j]) + b2*(L2n[j]-L2m[j]) + b3*(L3n[j]-L3m[j]);
    if (j == n) v += b0;
    if (j == m) v -= b0;
    He[j] = v;
  }
}

__device__ __forceinline__ void tri_decode(int p, int& ti, int& tj){
  ti = (int)((sqrtf(8.f*p + 1.f) - 1.f)*0.5f);
  while ((ti+1)*(ti+2)/2 <= p) ti++;
  while (ti*(ti+1)/2 > p) ti--;
  tj = p - ti*(ti+1)/2;
}

// Spart[z][p] = (Ht^T diag(sg) Ht) 64x64 tile (ti,tj), K-chunk z. f32 loads, f64 LDS + acc.
__global__ __launch_bounds__(256,2) void k_sgemm2(const float* __restrict__ Ht, const float* __restrict__ sg,
                                                  double* __restrict__ Spart){
  int p = blockIdx.x, z = blockIdx.y;
  int ti, tj; tri_decode(p, ti, tj);
  int i0 = ti*64, j0 = tj*64;
  __shared__ double As[32][66];
  __shared__ double Bs[32][66];
  int tid = threadIdx.x;
  int tx = tid & 15, ty = tid >> 4;
  double acc[4][4] = {};
  int kbase = z*(EE/KSPLIT);
  for (int k0 = kbase; k0 < kbase + EE/KSPLIT; k0 += 32){
#pragma unroll
    for (int l = 0; l < 2; ++l){
      int s = tid + 256*l;
      int kk = s >> 4, g = s & 15;
      const float* row = Ht + (size_t)(k0+kk)*NN;
      float4 va = *(const float4*)(row + i0 + g*4);
      float4 vb = *(const float4*)(row + j0 + g*4);
      double sgd = (double)sg[k0+kk];
      As[kk][g*4+0] = (double)va.x; As[kk][g*4+1] = (double)va.y;
      As[kk][g*4+2] = (double)va.z; As[kk][g*4+3] = (double)va.w;
      Bs[kk][g*4+0] = (double)vb.x*sgd; Bs[kk][g*4+1] = (double)vb.y*sgd;
      Bs[kk][g*4+2] = (double)vb.z*sgd; Bs[kk][g*4+3] = (double)vb.w*sgd;
    }
    __syncthreads();
#pragma unroll
    for (int kk = 0; kk < 32; ++kk){
      double av[4], bv[4];
#pragma unroll
      for (int q = 0; q < 4; ++q){ av[q] = As[kk][tx*4+q]; bv[q] = Bs[kk][ty*4+q]; }
#pragma unroll
      for (int r = 0; r < 4; ++r)
#pragma unroll
        for (int c = 0; c < 4; ++c)
          acc[r][c] += av[r]*bv[c];
    }
    __syncthreads();
  }
  double* out = Spart + ((size_t)z*NTILE + p)*4096;
#pragma unroll
  for (int r = 0; r < 4; ++r)
#pragma unroll
    for (int c = 0; c < 4; ++c)
      out[(tx*4+r)*64 + ty*4+c] = acc[r][c];
}

// Sd tile(ti,tj) = sum_z Spart + Cw  (lower tiles; diag tiles full square)
__global__ __launch_bounds__(256) void k_sreduce(const double* __restrict__ Spart, const float* __restrict__ Cw,
                                                 double* __restrict__ Sd){
  int p = blockIdx.x;
  int ti, tj; tri_decode(p, ti, tj);
  int tid = threadIdx.x;
  for (int idx = tid; idx < 4096; idx += 256){
    int r = idx >> 6, c = idx & 63;
    size_t gi = ti*64 + r, gj = tj*64 + c;
    double v = (double)Cw[gi*NN + gj];
#pragma unroll
    for (int z = 0; z < KSPLIT; ++z)
      v += Spart[((size_t)z*NTILE + p)*4096 + idx];
    Sd[gi*NN + gj] = v;
  }
}

// r = y - sum_p a_p c_p  (f64 out)
__global__ __launch_bounds__(256) void k_rvec(const float* __restrict__ y, const float* __restrict__ cb,
                                              const float* __restrict__ a, double* __restrict__ rz){
  int i = blockIdx.x*256 + threadIdx.x;
  if (i < NN){
    double acc = (double)y[i];
    for (int p = 0; p < 5; ++p) acc -= (double)a[p]*(double)cb[p*NN + i];
    rz[i] = acc;
  }
}

// =============== DAG-scheduled LDL^T factorization + single-block solve ===============
// Tile (I,J) (I>=J, 64x64) owned by block p=I(I+1)/2+J. Diag tiles store L(unit,divided) lower,
// d on diag, unit L^T upper. Panels stored divided. grd=1/d, dvals=d.
// Sync: relaxed-poll on flags + ONE acquire fence per dependency edge (no per-iteration L2 inv).
// Block NTILE runs the full triangular solve itself (sole owner of rz; no atomics, no hops).
__global__ __launch_bounds__(256) void k_fact(double* __restrict__ Sd, double* __restrict__ rz,
                                              double* __restrict__ grd, double* __restrict__ dvals,
                                              int* __restrict__ fl){
  __shared__ double T[BD][BD+1];
  __shared__ double R[BD][BD+1];
  __shared__ double dsh[BD];
  __shared__ double zsh[BD];
  __shared__ double ps[BD][5];
  int bid = blockIdx.x, tid = threadIdx.x;
  int tx = tid & 15, ty = tid >> 4;

  auto poll_one = [&](int slot){
    int it = 0;
    while (__hip_atomic_load(&fl[slot*16], __ATOMIC_RELAXED, __HIP_MEMORY_SCOPE_AGENT) == 0 && it < 30000000){
      __builtin_amdgcn_s_sleep(2); ++it;
    }
  };
  auto wait2 = [&](int s1, int s2){
    if (tid == 0){
      poll_one(s1);
      if (s2 >= 0) poll_one(s2);
      __builtin_amdgcn_fence(__ATOMIC_ACQUIRE, "agent");
    }
    __syncthreads();
  };
  auto set_slot = [&](int slot){
    __syncthreads();
    if (tid == 0){
      __builtin_amdgcn_fence(__ATOMIC_RELEASE, "agent");
      __hip_atomic_store(&fl[slot*16], 1, __ATOMIC_RELAXED, __HIP_MEMORY_SCOPE_AGENT);
    }
  };

  if (bid < NTILE){
    int I, J; tri_decode(bid, I, J);
    int i64 = I*64, j64 = J*64;
    // own tile -> registers (via coalesced LDS staging)
    double acc[4][4];
    for (int idx = tid; idx < 4096; idx += 256){
      int r = idx >> 6, c = idx & 63;
      R[r][c] = Sd[(size_t)(i64+r)*NN + j64 + c];
    }
    __syncthreads();
#pragma unroll
    for (int q = 0; q < 4; ++q)
#pragma unroll
      for (int p2 = 0; p2 < 4; ++p2) acc[q][p2] = R[tx*4+q][ty*4+p2];
    __syncthreads();

    // trailing updates: acc -= P(I,t) * D(t) * P(J,t)^T   for t < J
    for (int t = 0; t < J; ++t){
      int t64 = t*64;
      wait2(I*(I+1)/2 + t, (I != J) ? (J*(J+1)/2 + t) : -1);
      for (int idx = tid; idx < 4096; idx += 256){
        int r = idx >> 6, c = idx & 63;
        T[r][c] = Sd[(size_t)(i64+r)*NN + t64 + c];
        R[r][c] = Sd[(size_t)(j64+r)*NN + t64 + c] * dvals[t64+c];
      }
      __syncthreads();
      for (int k = 0; k < 64; ++k){
        double av[4], bv[4];
#pragma unroll
        for (int q = 0; q < 4; ++q){ av[q] = T[tx*4+q][k]; bv[q] = R[ty*4+q][k]; }
#pragma unroll
        for (int r = 0; r < 4; ++r)
#pragma unroll
          for (int c = 0; c < 4; ++c)
            acc[r][c] -= av[r]*bv[c];
      }
      __syncthreads();
    }

    if (I == J){
      // materialize into T, factor, write back + d
#pragma unroll
      for (int q = 0; q < 4; ++q)
#pragma unroll
        for (int p2 = 0; p2 < 4; ++p2) T[tx*4+q][ty*4+p2] = acc[q][p2];
      __syncthreads();
      for (int j = 0; j < BD; ++j){
        double dj = T[j][j];
        int fi = tid & 63, cg = tid >> 6;
        if (fi > j){
          double l = T[j][fi]/dj;
          for (int c = j+1+cg; c < BD; c += 4) T[fi][c] -= l*T[j][c];
        }
        __syncthreads();
      }
      if (tid < BD) dsh[tid] = 1.0 / T[tid][tid];
      __syncthreads();
      for (int idx = tid; idx < BD*BD; idx += 256){
        int r = idx >> 6, c = idx & 63;
        double v = (r == c) ? T[r][r] : (r > c ? T[r][c]*dsh[c] : T[r][c]*dsh[r]);
        Sd[(size_t)(i64+r)*NN + i64 + c] = v;
      }
      if (tid < BD){ grd[i64+tid] = dsh[tid]; dvals[i64+tid] = T[tid][tid]; }
      set_slot(bid);
    } else {
      // materialize into R, trsm vs factored diag J, divide, write
#pragma unroll
      for (int q = 0; q < 4; ++q)
#pragma unroll
        for (int p2 = 0; p2 < 4; ++p2) R[tx*4+q][ty*4+p2] = acc[q][p2];
      wait2(J*(J+1)/2 + J, -1);
      for (int idx = tid; idx < 4096; idx += 256){
        int r = idx >> 6, c = idx & 63;
        T[r][c] = Sd[(size_t)(j64+r)*NN + j64 + c];
      }
      if (tid < BD) dsh[tid] = grd[j64+tid];
      __syncthreads();
      for (int c0 = 0; c0 < BD; c0 += 16){
        if (tid < BD){
          for (int jj = 0; jj < 16; ++jj){
            int j = c0 + jj;
            double a2 = R[tid][j];
            for (int k = 0; k < jj; ++k) a2 -= R[tid][c0+k]*T[j][c0+k];
            R[tid][j] = a2;
          }
        }
        __syncthreads();
        if (c0 + 16 < BD){
          int r2 = tid & 63, jg = tid >> 6;
          for (int j = c0+16+jg; j < BD; j += 4){
            double a2 = R[r2][j];
#pragma unroll
            for (int k = 0; k < 16; ++k) a2 -= R[r2][c0+k]*T[j][c0+k];
            R[r2][j] = a2;
          }
        }
        __syncthreads();
      }
      for (int idx = tid; idx < 4096; idx += 256){
        int r = idx >> 6, c = idx & 63;
        Sd[(size_t)(i64+r)*NN + j64 + c] = R[r][c]*dsh[c];
      }
      set_slot(bid);
    }
  } else {
    // =============== single-block triangular solve ===============
    int lane = tid & 63, wv = tid >> 6;
    // -------- forward: L u = r (unit lower; diag upper = unit L^T) --------
    for (int t = 0; t < NB; ++t){
      int t64 = t*64;
      // wait for all column-t tiles (diag t + panels (I,t)); one fence
      if (tid == 0){
        for (int I = t; I < NB; ++I) poll_one(I*(I+1)/2 + t);
        __builtin_amdgcn_fence(__ATOMIC_ACQUIRE, "agent");
      }
      __syncthreads();
      for (int idx = tid; idx < BD*BD; idx += 256){
        int r = idx >> 6, c = idx & 63;
        T[r][c] = Sd[(size_t)(t64+r)*NN + t64 + c];
      }
      __syncthreads();
      if (wv == 0){
        double x = rz[t64 + lane];
        for (int j = 0; j < BD-1; ++j){
          double xj = __shfl(x, j, 64);
          if (lane > j) x -= T[j][lane]*xj;      // upper = unit L^T
        }
        zsh[lane] = x;
        rz[t64 + lane] = x;
      }
      __syncthreads();
      // update all rows below: wave-per-row, coalesced, 16 rows in flight
      for (int g0 = t64 + BD + wv*4; g0 < NN; g0 += 16){
        double v0 = Sd[(size_t)(g0+0)*NN + t64 + lane]*zsh[lane];
        double v1 = Sd[(size_t)(g0+1)*NN + t64 + lane]*zsh[lane];
        double v2 = Sd[(size_t)(g0+2)*NN + t64 + lane]*zsh[lane];
        double v3 = Sd[(size_t)(g0+3)*NN + t64 + lane]*zsh[lane];
        v0 = waveReduceD(v0); v1 = waveReduceD(v1);
        v2 = waveReduceD(v2); v3 = waveReduceD(v3);
        if (lane == 0){
          rz[g0+0] -= v0; rz[g0+1] -= v1; rz[g0+2] -= v2; rz[g0+3] -= v3;
        }
      }
      __syncthreads();
    }
    // -------- diagonal: w = u / d --------
    for (int i = tid; i < NN; i += 256) rz[i] *= grd[i];
    __syncthreads();
    // -------- backward: L^T x = w --------
    for (int t = NB-1; t >= 0; --t){
      int t64 = t*64;
      for (int idx = tid; idx < BD*BD; idx += 256){
        int r = idx >> 6, c = idx & 63;
        T[r][c] = Sd[(size_t)(t64+r)*NN + t64 + c];
      }
      __syncthreads();
      if (wv == 0){
        double x = rz[t64 + lane];
        for (int j = BD-1; j >= 1; --j){
          double xj = __shfl(x, j, 64);
          if (lane < j) x -= T[j][lane]*xj;      // lower = unit L
        }
        zsh[lane] = x;
        rz[t64 + lane] = x;
      }
      __syncthreads();
      // update earlier blocks: rz[J] -= L(t,J)^T x_t, column-partial sums
      for (int J = 0; J < t; ++J){
        int j64 = J*64;
        double a2 = 0.0;
#pragma unroll
        for (int k = 0; k < 16; ++k){
          int r = wv*16 + k;
          a2 += Sd[(size_t)(t64+r)*NN + j64 + lane]*zsh[r];
        }
        ps[lane][wv] = a2;
        __syncthreads();
        if (tid < BD) rz[j64+tid] -= ps[tid][0]+ps[tid][1]+ps[tid][2]+ps[tid][3];
        __syncthreads();
      }
    }
  }
}

// s_out = relu(s + sigma .* (Ht z))
__global__ __launch_bounds__(256) void k_snew(const float* __restrict__ Ht, const float* __restrict__ sv,
                                              const float* __restrict__ sg, const double* __restrict__ z,
                                              float* __restrict__ out){
  int e = blockIdx.x*4 + (threadIdx.x >> 6);
  int lane = threadIdx.x & 63;
  const float* He = Ht + (size_t)e*NN;
  double acc = 0.0;
  for (int j = lane; j < NN; j += 64) acc += (double)He[j]*z[j];
  acc = waveReduceD(acc);
  if (lane == 0){
    double val = (double)sv[e] + (double)sg[e]*acc;
    out[e] = fmaxf((float)val, 0.0f);
  }
}

extern "C" void kernel_launch(void* const* d_in, const int* in_sizes, int n_in,
                              void* d_out, int out_size, void* d_ws, size_t ws_size,
                              hipStream_t stream){
  const float* q   = (const float*)d_in[0];
  const float* y   = (const float*)d_in[1];
  const float* F   = (const float*)d_in[2];
  // d_in[3] = B (incidence) — structure carried by edges
  const int*   edges = (const int*)d_in[4];
  const float* Cu  = (const float*)d_in[5];
  const float* Cw  = (const float*)d_in[6];
  const float* s0  = (const float*)d_in[7];
  const float* Sg0 = (const float*)d_in[8];
  const float* a   = (const float*)d_in[9];
  float* out = (float*)d_out;

  double* Sd    = (double*)d_ws;                       // 8 MB
  double* Spart = Sd + (size_t)NN*NN;                  // 17.8 MB
  double* rz    = Spart + (size_t)KSPLIT*NTILE*4096;
  double* grd   = rz + NN;
  double* dvals = grd + NN;
  float* w = (float*)(dvals + NN);
  float* L  = w; w += (size_t)NN*NN;
  float* L2 = w; w += (size_t)NN*NN;
  float* L3 = w; w += (size_t)NN*NN;
  float* Ht = w; w += (size_t)EE*NN;
  float* cb = w; w += 5*NN;
  float* sv = w; w += EE;
  float* sg = w; w += EE;
  float* bt = w; w += 4*EE;
  float* wg = w; w += (size_t)NN*CAP;
  int* cnt  = (int*)w; w += NN;
  int* nb   = (int*)w; w += (size_t)NN*CAP;
  int* fl   = (int*)w; w += NSLOT*16;

  hipMemsetAsync(L, 0, (size_t)NN*NN*sizeof(float), stream);
  hipMemsetAsync(cnt, 0, NN*sizeof(int), stream);
  hipMemsetAsync(fl, 0, NSLOT*16*sizeof(int), stream);

  k_edge_init<<<EE/256, 256, 0, stream>>>(F, Sg0, Cu, s0, sv, sg);
  k_scatter<<<EE/256, 256, 0, stream>>>(edges, sv, L, cnt, nb, wg);

  hipMemcpyAsync(cb, q, NN*sizeof(float), hipMemcpyDeviceToDevice, stream);
  for (int p = 1; p < 5; ++p)
    k_spmv<<<NN/256, 256, 0, stream>>>(L, cnt, nb, wg, cb + (p-1)*NN, cb + p*NN);

  k_srow<<<NN, 256, 0, stream>>>(L, cnt, nb, wg, L,  L2);
  k_srow<<<NN, 256, 0, stream>>>(L, cnt, nb, wg, L2, L3);

  k_beta<<<EE/256, 256, 0, stream>>>(edges, cb, a, bt);
  k_hbuild<<<EE, 256, 0, stream>>>(edges, bt, L, L2, L3, Ht);

  dim3 gg(NTILE, KSPLIT);
  k_sgemm2<<<gg, 256, 0, stream>>>(Ht, sg, Spart);
  k_sreduce<<<NTILE, 256, 0, stream>>>(Spart, Cw, Sd);

  k_rvec<<<NN/256, 256, 0, stream>>>(y, cb, a, rz);

  k_fact<<<NTILE+1, 256, 0, stream>>>(Sd, rz, grd, dvals, fl);

  k_snew<<<EE/4, 256, 0, stream>>>(Ht, sv, sg, rz, out);
}